// Round 3
// baseline (755.247 us; speedup 1.0000x reference)
//
#include <hip/hip_runtime.h>
#include <hip/hip_bf16.h>

typedef __attribute__((ext_vector_type(8))) short bf16x8;
typedef __attribute__((ext_vector_type(4))) float f32x4;

#define MFMA_16x16x32(a,b,c) __builtin_amdgcn_mfma_f32_16x16x32_bf16((a),(b),(c),0,0,0)

__device__ __forceinline__ unsigned short f2b(float f){
  unsigned int u = __builtin_bit_cast(unsigned int, f);
  u = u + 0x7FFFu + ((u >> 16) & 1u);
  return (unsigned short)(u >> 16);
}
__device__ __forceinline__ float b2f(unsigned short h){
  unsigned int u = ((unsigned int)h) << 16;
  return __builtin_bit_cast(float, u);
}

// ---------------- elementwise converters ----------------

__global__ void cvt_f32_bf16(const float* __restrict__ src, unsigned short* __restrict__ dst, int n4){
  int i = blockIdx.x * blockDim.x + threadIdx.x;
  int stride = gridDim.x * blockDim.x;
  for (; i < n4; i += stride){
    float4 v = reinterpret_cast<const float4*>(src)[i];
    ushort4 o;
    o.x = f2b(v.x); o.y = f2b(v.y); o.z = f2b(v.z); o.w = f2b(v.w);
    reinterpret_cast<ushort4*>(dst)[i] = o;
  }
}

// src (Hn,64,128) f32 -> dst (Hn,128,64) bf16 (transpose r<->d per head)
__global__ void cvt_factor_t(const float* __restrict__ src, unsigned short* __restrict__ dst, int n){
  int i = blockIdx.x * blockDim.x + threadIdx.x;
  if (i >= n) return;
  int d = i & 127, r = (i >> 7) & 63, h = i >> 13;
  dst[(h << 13) + (d << 6) + r] = f2b(src[i]);
}

// in-place RoPE on (BH,2048,128) bf16; fc/fs are (2048,64) f32
__global__ void rope_inplace(unsigned short* __restrict__ buf,
                             const float* __restrict__ fc,
                             const float* __restrict__ fs, int total){
  int i = blockIdx.x * blockDim.x + threadIdx.x;
  if (i >= total) return;
  int d4 = (i & 15) << 2;           // 0,4,...,60
  int s  = (i >> 4) & 2047;
  size_t base = ((size_t)(i >> 4)) * 128;   // (bh*2048+s)*128
  ushort4 x1 = *reinterpret_cast<ushort4*>(buf + base + d4);
  ushort4 x2 = *reinterpret_cast<ushort4*>(buf + base + 64 + d4);
  float4 c  = *reinterpret_cast<const float4*>(fc + (size_t)s*64 + d4);
  float4 sn = *reinterpret_cast<const float4*>(fs + (size_t)s*64 + d4);
  ushort4 o1, o2; float a, b;
  a = b2f(x1.x); b = b2f(x2.x); o1.x = f2b(a*c.x - b*sn.x); o2.x = f2b(a*sn.x + b*c.x);
  a = b2f(x1.y); b = b2f(x2.y); o1.y = f2b(a*c.y - b*sn.y); o2.y = f2b(a*sn.y + b*c.y);
  a = b2f(x1.z); b = b2f(x2.z); o1.z = f2b(a*c.z - b*sn.z); o2.z = f2b(a*sn.z + b*c.z);
  a = b2f(x1.w); b = b2f(x2.w); o1.w = f2b(a*c.w - b*sn.w); o2.w = f2b(a*sn.w + b*c.w);
  *reinterpret_cast<ushort4*>(buf + base + d4)      = o1;
  *reinterpret_cast<ushort4*>(buf + base + 64 + d4) = o2;
}

// ---------------- big GEMM-BT: C(MxN) = A(MxK) @ B(NxK)^T, bf16 in ----------------
// 128x128 tile, BK=64, 4 waves (2x2), reg-staged pipeline, XOR-swizzled LDS.

template<int OUT_F32>
__global__ __launch_bounds__(256) void gemm_bt(
    const unsigned short* __restrict__ A, const unsigned short* __restrict__ B,
    void* __restrict__ Cv, int N, int K, float scale)
{
  __shared__ unsigned short As[128*64];
  __shared__ unsigned short Bs[128*64];
  const int tid = threadIdx.x;
  const int mb = blockIdx.x, nb = blockIdx.y;
  const int w = tid >> 6, lane = tid & 63;
  const int wr = w >> 1, wc = w & 1;
  const int l16 = lane & 15, lg = lane >> 4;

  f32x4 acc[4][4] = {};

  const int srow = tid >> 3;          // 0..31
  const int scol = (tid & 7) << 3;    // 0..56

  const unsigned short* Ap = A + (size_t)(mb*128)*K;
  const unsigned short* Bp = B + (size_t)(nb*128)*K;

  bf16x8 ar[4], br[4];
  #pragma unroll
  for (int c = 0; c < 4; c++){
    ar[c] = *reinterpret_cast<const bf16x8*>(Ap + (size_t)(srow + 32*c)*K + scol);
    br[c] = *reinterpret_cast<const bf16x8*>(Bp + (size_t)(srow + 32*c)*K + scol);
  }
  const int nkt = K >> 6;
  for (int kt = 0; kt < nkt; kt++){
    __syncthreads();
    #pragma unroll
    for (int c = 0; c < 4; c++){
      int r = srow + 32*c;
      int idx = (r*64 + scol) ^ ((r & 7) << 3);
      *reinterpret_cast<bf16x8*>(&As[idx]) = ar[c];
      *reinterpret_cast<bf16x8*>(&Bs[idx]) = br[c];
    }
    __syncthreads();
    if (kt + 1 < nkt){
      const unsigned short* Ap2 = Ap + (size_t)(kt+1)*64;
      const unsigned short* Bp2 = Bp + (size_t)(kt+1)*64;
      #pragma unroll
      for (int c = 0; c < 4; c++){
        ar[c] = *reinterpret_cast<const bf16x8*>(Ap2 + (size_t)(srow + 32*c)*K + scol);
        br[c] = *reinterpret_cast<const bf16x8*>(Bp2 + (size_t)(srow + 32*c)*K + scol);
      }
    }
    #pragma unroll
    for (int t = 0; t < 2; t++){
      bf16x8 af[4], bf[4];
      #pragma unroll
      for (int i = 0; i < 4; i++){
        int rowA = wr*64 + i*16 + l16;
        int col  = t*32 + lg*8;
        af[i] = *reinterpret_cast<const bf16x8*>(&As[(rowA*64 + col) ^ ((rowA & 7) << 3)]);
        int rowB = wc*64 + i*16 + l16;
        bf[i] = *reinterpret_cast<const bf16x8*>(&Bs[(rowB*64 + col) ^ ((rowB & 7) << 3)]);
      }
      #pragma unroll
      for (int i = 0; i < 4; i++)
        #pragma unroll
        for (int j = 0; j < 4; j++)
          acc[i][j] = MFMA_16x16x32(af[i], bf[j], acc[i][j]);
    }
  }
  #pragma unroll
  for (int i = 0; i < 4; i++){
    #pragma unroll
    for (int j = 0; j < 4; j++){
      int row = mb*128 + wr*64 + i*16 + lg*4;
      int col = nb*128 + wc*64 + j*16 + l16;
      #pragma unroll
      for (int r = 0; r < 4; r++){
        float v = acc[i][j][r] * scale;
        if (OUT_F32) reinterpret_cast<float*>(Cv)[(size_t)(row + r)*N + col] = v;
        else reinterpret_cast<unsigned short*>(Cv)[(size_t)(row + r)*N + col] = f2b(v);
      }
    }
  }
}

// ---------------- factor GEMM: per-head C(4096x128) = A(:,off+h*64 ..+64) @ Bt[h](128x64)^T ----------------
// Out layout (B,Hn,2048,128) bf16, scaled.

__global__ __launch_bounds__(256) void factor_gemm(
    const unsigned short* __restrict__ A,    // (4096,2048) bf16
    const unsigned short* __restrict__ Bt,   // (Hn,128,64) bf16
    unsigned short* __restrict__ Out, int coloff, int Hn, float scale)
{
  __shared__ unsigned short As[128*64];
  __shared__ unsigned short Bs[128*64];
  const int tid = threadIdx.x;
  const int mb = blockIdx.x;     // 0..31
  const int h  = blockIdx.y;     // 0..Hn-1
  const int w = tid >> 6, lane = tid & 63;
  const int wr = w >> 1, wc = w & 1;
  const int l16 = lane & 15, lg = lane >> 4;

  const int srow = tid >> 3;
  const int scol = (tid & 7) << 3;

  const unsigned short* Ap = A + (size_t)(mb*128)*2048 + coloff + h*64;
  const unsigned short* Bp = Bt + (size_t)h*(128*64);

  #pragma unroll
  for (int c = 0; c < 4; c++){
    int r = srow + 32*c;
    int idx = (r*64 + scol) ^ ((r & 7) << 3);
    *reinterpret_cast<bf16x8*>(&As[idx]) = *reinterpret_cast<const bf16x8*>(Ap + (size_t)r*2048 + scol);
    *reinterpret_cast<bf16x8*>(&Bs[idx]) = *reinterpret_cast<const bf16x8*>(Bp + r*64 + scol);
  }
  __syncthreads();

  f32x4 acc[4][4] = {};
  #pragma unroll
  for (int t = 0; t < 2; t++){
    bf16x8 af[4], bf[4];
    #pragma unroll
    for (int i = 0; i < 4; i++){
      int rowA = wr*64 + i*16 + l16;
      int col  = t*32 + lg*8;
      af[i] = *reinterpret_cast<const bf16x8*>(&As[(rowA*64 + col) ^ ((rowA & 7) << 3)]);
      int rowB = wc*64 + i*16 + l16;
      bf[i] = *reinterpret_cast<const bf16x8*>(&Bs[(rowB*64 + col) ^ ((rowB & 7) << 3)]);
    }
    #pragma unroll
    for (int i = 0; i < 4; i++)
      #pragma unroll
      for (int j = 0; j < 4; j++)
        acc[i][j] = MFMA_16x16x32(af[i], bf[j], acc[i][j]);
  }

  #pragma unroll
  for (int i = 0; i < 4; i++){
    #pragma unroll
    for (int j = 0; j < 4; j++){
      int row0 = mb*128 + wr*64 + i*16 + lg*4;
      int d    = wc*64 + j*16 + l16;
      #pragma unroll
      for (int r = 0; r < 4; r++){
        int row = row0 + r;
        int b = row >> 11, s = row & 2047;
        Out[((size_t)(b*Hn + h)*2048 + s)*128 + d] = f2b(acc[i][j][r] * scale);
      }
    }
  }
}

// ---------------- flash attention (causal, GQA 2:1) ----------------
// grid (32 qb, 16 h, 2 b); 4 waves x 16 q-rows; KV block = 64.

__device__ __forceinline__ int vt_idx(int d, int kv){
  // Vt logical [128 d][64 kv]; rotate 8-elem chunks so both transpose-writes
  // (d varies per lane) and b128 reads (d varies per lane, kv chunk fixed) are <=2-way.
  return d*64 + ((((kv >> 3) + d + (d >> 3)) & 7) << 3) + (kv & 7);
}

__global__ __launch_bounds__(256) void flash_attn(
    const unsigned short* __restrict__ Q,   // (B,16,2048,128) roped, pre-scaled by SCALE/RQ
    const unsigned short* __restrict__ Kb,  // (B,8,2048,128) roped, /RK
    const unsigned short* __restrict__ Vb,  // (B,8,2048,128) /RV
    unsigned short* __restrict__ O)         // (B*2048, 2048), col = h*128+d
{
  __shared__ unsigned short Ks[64*128];
  __shared__ unsigned short Vt[128*64];
  __shared__ unsigned short Pl[4][16*64];

  const int tid = threadIdx.x;
  const int w = tid >> 6, lane = tid & 63;
  const int l16 = lane & 15, lg = lane >> 4;
  const int qb = (int)gridDim.x - 1 - blockIdx.x;   // reverse: heavy blocks first
  const int h = blockIdx.y, b = blockIdx.z;
  const int hkv = h >> 1;

  const size_t qbase = (((size_t)(b*16 + h))*2048 + qb*64 + w*16)*128;
  const size_t kbase = ((size_t)(b*8 + hkv))*2048*128;

  bf16x8 aq[4];
  #pragma unroll
  for (int t = 0; t < 4; t++)
    aq[t] = *reinterpret_cast<const bf16x8*>(&Q[qbase + (size_t)l16*128 + t*32 + lg*8]);

  f32x4 oac[8] = {};
  float mrow[4], lrow[4];
  #pragma unroll
  for (int r = 0; r < 4; r++){ mrow[r] = -1e30f; lrow[r] = 0.f; }
  const int qrow0 = qb*64 + w*16 + lg*4;

  for (int kb = 0; kb <= qb; kb++){
    __syncthreads();   // previous iteration's LDS reads done
    #pragma unroll
    for (int c = 0; c < 4; c++){
      int e = c*2048 + tid*8;
      int row = e >> 7, col = e & 127;
      bf16x8 kv = *reinterpret_cast<const bf16x8*>(&Kb[kbase + (size_t)(kb*64 + row)*128 + col]);
      *reinterpret_cast<bf16x8*>(&Ks[(row*128 + col) ^ ((row & 7) << 3)]) = kv;
      bf16x8 vv = *reinterpret_cast<const bf16x8*>(&Vb[kbase + (size_t)(kb*64 + row)*128 + col]);
      #pragma unroll
      for (int j = 0; j < 8; j++)
        Vt[vt_idx(col + j, row)] = (unsigned short)vv[j];
    }
    __syncthreads();

    // S (16q x 64k) = Q @ K^T
    f32x4 sac[4] = {};
    #pragma unroll
    for (int nt = 0; nt < 4; nt++){
      #pragma unroll
      for (int t = 0; t < 4; t++){
        int rowK = nt*16 + l16;
        int col  = t*32 + lg*8;
        bf16x8 bk = *reinterpret_cast<const bf16x8*>(&Ks[(rowK*128 + col) ^ ((rowK & 7) << 3)]);
        sac[nt] = MFMA_16x16x32(aq[t], bk, sac[nt]);
      }
    }
    if (kb == qb){
      #pragma unroll
      for (int nt = 0; nt < 4; nt++){
        int kcol = kb*64 + nt*16 + l16;
        #pragma unroll
        for (int r = 0; r < 4; r++)
          if (kcol > qrow0 + r) sac[nt][r] = -1e30f;
      }
    }
    // online softmax (rows live in 16-lane groups: shfl_xor 1/2/4/8)
    float corr[4];
    #pragma unroll
    for (int r = 0; r < 4; r++){
      float v = fmaxf(fmaxf(sac[0][r], sac[1][r]), fmaxf(sac[2][r], sac[3][r]));
      v = fmaxf(v, __shfl_xor(v, 1));
      v = fmaxf(v, __shfl_xor(v, 2));
      v = fmaxf(v, __shfl_xor(v, 4));
      v = fmaxf(v, __shfl_xor(v, 8));
      float mn = fmaxf(mrow[r], v);
      corr[r] = __expf(mrow[r] - mn);
      mrow[r] = mn;
    }
    float rs[4] = {0.f, 0.f, 0.f, 0.f};
    #pragma unroll
    for (int nt = 0; nt < 4; nt++){
      #pragma unroll
      for (int r = 0; r < 4; r++){
        float p = __expf(sac[nt][r] - mrow[r]);
        sac[nt][r] = p;
        rs[r] += p;
      }
    }
    #pragma unroll
    for (int r = 0; r < 4; r++){
      float v = rs[r];
      v += __shfl_xor(v, 1); v += __shfl_xor(v, 2); v += __shfl_xor(v, 4); v += __shfl_xor(v, 8);
      lrow[r] = lrow[r]*corr[r] + v;
    }
    #pragma unroll
    for (int dn = 0; dn < 8; dn++)
      #pragma unroll
      for (int r = 0; r < 4; r++) oac[dn][r] *= corr[r];

    // P -> LDS (wave-private), then PV
    #pragma unroll
    for (int nt = 0; nt < 4; nt++){
      #pragma unroll
      for (int r = 0; r < 4; r++){
        int row = lg*4 + r, col = nt*16 + l16;
        Pl[w][(row*64 + col) ^ ((row & 7) << 3)] = f2b(sac[nt][r]);
      }
    }
    asm volatile("s_waitcnt lgkmcnt(0)" ::: "memory");
    __builtin_amdgcn_sched_barrier(0);
    #pragma unroll
    for (int t = 0; t < 2; t++){
      int colp = t*32 + lg*8;
      bf16x8 ap = *reinterpret_cast<const bf16x8*>(&Pl[w][(l16*64 + colp) ^ ((l16 & 7) << 3)]);
      #pragma unroll
      for (int dn = 0; dn < 8; dn++){
        int rowV = dn*16 + l16;
        bf16x8 bv = *reinterpret_cast<const bf16x8*>(&Vt[vt_idx(rowV, colp)]);
        oac[dn] = MFMA_16x16x32(ap, bv, oac[dn]);
      }
    }
  }

  #pragma unroll
  for (int dn = 0; dn < 8; dn++){
    #pragma unroll
    for (int r = 0; r < 4; r++){
      int row = qb*64 + w*16 + lg*4 + r;
      O[((size_t)(b*2048 + row))*2048 + h*128 + dn*16 + l16] = f2b(oac[dn][r] / lrow[r]);
    }
  }
}

// ---------------- launcher ----------------

extern "C" void kernel_launch(void* const* d_in, const int* in_sizes, int n_in,
                              void* d_out, int out_size, void* d_ws, size_t ws_size,
                              hipStream_t stream)
{
  if (n_in < 10) return;
  const float* hidden = (const float*)d_in[0];
  const float* WAq = (const float*)d_in[1];
  const float* WAk = (const float*)d_in[2];
  const float* WAv = (const float*)d_in[3];
  const float* Bq  = (const float*)d_in[4];
  const float* Bk  = (const float*)d_in[5];
  const float* Bv  = (const float*)d_in[6];
  const float* Wo  = (const float*)d_in[7];
  const float* fcos = (const float*)d_in[8];
  const float* fsin = (const float*)d_in[9];
  float* out = (float*)d_out;

  char* p = (char*)d_ws;
  auto take = [&](size_t bytes){ char* q = p; p += (bytes + 255) & ~(size_t)255; return q; };
  unsigned short* Xb   = (unsigned short*)take((size_t)4096*2048*2);
  unsigned short* Wqkv = (unsigned short*)take((size_t)2048*2048*2);
  unsigned short* Wob  = (unsigned short*)take((size_t)2048*2048*2);
  unsigned short* Aqkv = (unsigned short*)take((size_t)4096*2048*2);
  unsigned short* Bqt  = (unsigned short*)take((size_t)16*128*64*2);
  unsigned short* Bkt  = (unsigned short*)take((size_t)8*128*64*2);
  unsigned short* Bvt  = (unsigned short*)take((size_t)8*128*64*2);
  unsigned short* qbuf = (unsigned short*)take((size_t)2*16*2048*128*2);
  unsigned short* kbuf = (unsigned short*)take((size_t)2*8*2048*128*2);
  unsigned short* vbuf = (unsigned short*)take((size_t)2*8*2048*128*2);
  unsigned short* aout = (unsigned short*)take((size_t)4096*2048*2);
  if ((size_t)(p - (char*)d_ws) > ws_size) return;  // ws too small: leave output poisoned (visible failure)

  auto cvt = [&](const float* s, unsigned short* d, size_t n){
    int n4 = (int)(n >> 2);
    int blocks = (n4 + 255) / 256; if (blocks > 4096) blocks = 4096;
    cvt_f32_bf16<<<blocks, 256, 0, stream>>>(s, d, n4);
  };
  cvt(hidden, Xb, (size_t)4096*2048);
  cvt(WAq, Wqkv,                       (size_t)1024*2048);
  cvt(WAk, Wqkv + (size_t)1024*2048,   (size_t)512*2048);
  cvt(WAv, Wqkv + (size_t)1536*2048,   (size_t)512*2048);
  cvt(Wo,  Wob, (size_t)2048*2048);
  cvt_factor_t<<<(16*64*128)/256, 256, 0, stream>>>(Bq, Bqt, 16*64*128);
  cvt_factor_t<<<(8*64*128)/256, 256, 0, stream>>>(Bk, Bkt, 8*64*128);
  cvt_factor_t<<<(8*64*128)/256, 256, 0, stream>>>(Bv, Bvt, 8*64*128);

  // A-factors: (4096,2048) = Xb @ Wqkv^T
  gemm_bt<0><<<dim3(32,16), 256, 0, stream>>>(Xb, Wqkv, (void*)Aqkv, 2048, 2048, 1.0f);

  const float SCALE = 0.08838834764831845f;  // 128^-0.5
  factor_gemm<<<dim3(32,16), 256, 0, stream>>>(Aqkv, Bqt, qbuf, 0,    16, SCALE/64.0f);
  factor_gemm<<<dim3(32,8),  256, 0, stream>>>(Aqkv, Bkt, kbuf, 1024, 8,  1.0f/64.0f);
  factor_gemm<<<dim3(32,8),  256, 0, stream>>>(Aqkv, Bvt, vbuf, 1536, 8,  1.0f/64.0f);

  rope_inplace<<<(32*2048*16)/256, 256, 0, stream>>>(qbuf, fcos, fsin, 32*2048*16);
  rope_inplace<<<(16*2048*16)/256, 256, 0, stream>>>(kbuf, fcos, fsin, 16*2048*16);

  flash_attn<<<dim3(32,16,2), 256, 0, stream>>>(qbuf, kbuf, vbuf, aout);

  // final: (4096,2048) fp32 = aout @ Wo^T
  gemm_bt<1><<<dim3(32,16), 256, 0, stream>>>(aout, Wob, (void*)out, 2048, 2048, 1.0f);
}

// Round 4
// 495.898 us; speedup vs baseline: 1.5230x; 1.5230x over previous
//
#include <hip/hip_runtime.h>
#include <hip/hip_bf16.h>

typedef __attribute__((ext_vector_type(8))) short bf16x8;
typedef __attribute__((ext_vector_type(4))) float f32x4;

#define MFMA_16x16x32(a,b,c) __builtin_amdgcn_mfma_f32_16x16x32_bf16((a),(b),(c),0,0,0)

__device__ __forceinline__ unsigned short f2b(float f){
  unsigned int u = __builtin_bit_cast(unsigned int, f);
  u = u + 0x7FFFu + ((u >> 16) & 1u);
  return (unsigned short)(u >> 16);
}
__device__ __forceinline__ float b2f(unsigned short h){
  unsigned int u = ((unsigned int)h) << 16;
  return __builtin_bit_cast(float, u);
}

__device__ __forceinline__ void gload_lds16(const unsigned short* g, unsigned short* l){
  __builtin_amdgcn_global_load_lds(
      (const __attribute__((address_space(1))) void*)g,
      (__attribute__((address_space(3))) void*)l, 16, 0, 0);
}

// ---------------- elementwise converters ----------------

__global__ void cvt_f32_bf16(const float* __restrict__ src, unsigned short* __restrict__ dst, int n4){
  int i = blockIdx.x * blockDim.x + threadIdx.x;
  int stride = gridDim.x * blockDim.x;
  for (; i < n4; i += stride){
    float4 v = reinterpret_cast<const float4*>(src)[i];
    ushort4 o;
    o.x = f2b(v.x); o.y = f2b(v.y); o.z = f2b(v.z); o.w = f2b(v.w);
    reinterpret_cast<ushort4*>(dst)[i] = o;
  }
}

// src (Hn,64,128) f32 -> dst (Hn,128,64) bf16 (transpose r<->d per head)
__global__ void cvt_factor_t(const float* __restrict__ src, unsigned short* __restrict__ dst, int n){
  int i = blockIdx.x * blockDim.x + threadIdx.x;
  if (i >= n) return;
  int d = i & 127, r = (i >> 7) & 63, h = i >> 13;
  dst[(h << 13) + (d << 6) + r] = f2b(src[i]);
}

// in-place RoPE on (BH,2048,128) bf16; fc/fs are (2048,64) f32
__global__ void rope_inplace(unsigned short* __restrict__ buf,
                             const float* __restrict__ fc,
                             const float* __restrict__ fs, int total){
  int i = blockIdx.x * blockDim.x + threadIdx.x;
  if (i >= total) return;
  int d4 = (i & 15) << 2;           // 0,4,...,60
  int s  = (i >> 4) & 2047;
  size_t base = ((size_t)(i >> 4)) * 128;   // (bh*2048+s)*128
  ushort4 x1 = *reinterpret_cast<ushort4*>(buf + base + d4);
  ushort4 x2 = *reinterpret_cast<ushort4*>(buf + base + 64 + d4);
  float4 c  = *reinterpret_cast<const float4*>(fc + (size_t)s*64 + d4);
  float4 sn = *reinterpret_cast<const float4*>(fs + (size_t)s*64 + d4);
  ushort4 o1, o2; float a, b;
  a = b2f(x1.x); b = b2f(x2.x); o1.x = f2b(a*c.x - b*sn.x); o2.x = f2b(a*sn.x + b*c.x);
  a = b2f(x1.y); b = b2f(x2.y); o1.y = f2b(a*c.y - b*sn.y); o2.y = f2b(a*sn.y + b*c.y);
  a = b2f(x1.z); b = b2f(x2.z); o1.z = f2b(a*c.z - b*sn.z); o2.z = f2b(a*sn.z + b*c.z);
  a = b2f(x1.w); b = b2f(x2.w); o1.w = f2b(a*c.w - b*sn.w); o2.w = f2b(a*sn.w + b*c.w);
  *reinterpret_cast<ushort4*>(buf + base + d4)      = o1;
  *reinterpret_cast<ushort4*>(buf + base + 64 + d4) = o2;
}

// ---------------- big GEMM-BT: C(MxN) = A(MxK) @ B(NxK)^T, bf16 in ----------------

template<int OUT_F32>
__global__ __launch_bounds__(256) void gemm_bt(
    const unsigned short* __restrict__ A, const unsigned short* __restrict__ B,
    void* __restrict__ Cv, int N, int K, float scale)
{
  __shared__ unsigned short As[128*64];
  __shared__ unsigned short Bs[128*64];
  const int tid = threadIdx.x;
  const int mb = blockIdx.x, nb = blockIdx.y;
  const int w = tid >> 6, lane = tid & 63;
  const int wr = w >> 1, wc = w & 1;
  const int l16 = lane & 15, lg = lane >> 4;

  f32x4 acc[4][4] = {};

  const int srow = tid >> 3;          // 0..31
  const int scol = (tid & 7) << 3;    // 0..56

  const unsigned short* Ap = A + (size_t)(mb*128)*K;
  const unsigned short* Bp = B + (size_t)(nb*128)*K;

  bf16x8 ar[4], br[4];
  #pragma unroll
  for (int c = 0; c < 4; c++){
    ar[c] = *reinterpret_cast<const bf16x8*>(Ap + (size_t)(srow + 32*c)*K + scol);
    br[c] = *reinterpret_cast<const bf16x8*>(Bp + (size_t)(srow + 32*c)*K + scol);
  }
  const int nkt = K >> 6;
  for (int kt = 0; kt < nkt; kt++){
    __syncthreads();
    #pragma unroll
    for (int c = 0; c < 4; c++){
      int r = srow + 32*c;
      int idx = (r*64 + scol) ^ ((r & 7) << 3);
      *reinterpret_cast<bf16x8*>(&As[idx]) = ar[c];
      *reinterpret_cast<bf16x8*>(&Bs[idx]) = br[c];
    }
    __syncthreads();
    if (kt + 1 < nkt){
      const unsigned short* Ap2 = Ap + (size_t)(kt+1)*64;
      const unsigned short* Bp2 = Bp + (size_t)(kt+1)*64;
      #pragma unroll
      for (int c = 0; c < 4; c++){
        ar[c] = *reinterpret_cast<const bf16x8*>(Ap2 + (size_t)(srow + 32*c)*K + scol);
        br[c] = *reinterpret_cast<const bf16x8*>(Bp2 + (size_t)(srow + 32*c)*K + scol);
      }
    }
    #pragma unroll
    for (int t = 0; t < 2; t++){
      bf16x8 af[4], bf[4];
      #pragma unroll
      for (int i = 0; i < 4; i++){
        int rowA = wr*64 + i*16 + l16;
        int col  = t*32 + lg*8;
        af[i] = *reinterpret_cast<const bf16x8*>(&As[(rowA*64 + col) ^ ((rowA & 7) << 3)]);
        int rowB = wc*64 + i*16 + l16;
        bf[i] = *reinterpret_cast<const bf16x8*>(&Bs[(rowB*64 + col) ^ ((rowB & 7) << 3)]);
      }
      #pragma unroll
      for (int i = 0; i < 4; i++)
        #pragma unroll
        for (int j = 0; j < 4; j++)
          acc[i][j] = MFMA_16x16x32(af[i], bf[j], acc[i][j]);
    }
  }
  #pragma unroll
  for (int i = 0; i < 4; i++){
    #pragma unroll
    for (int j = 0; j < 4; j++){
      int row = mb*128 + wr*64 + i*16 + lg*4;
      int col = nb*128 + wc*64 + j*16 + l16;
      #pragma unroll
      for (int r = 0; r < 4; r++){
        float v = acc[i][j][r] * scale;
        if (OUT_F32) reinterpret_cast<float*>(Cv)[(size_t)(row + r)*N + col] = v;
        else reinterpret_cast<unsigned short*>(Cv)[(size_t)(row + r)*N + col] = f2b(v);
      }
    }
  }
}

// ---------------- factor GEMM ----------------

__global__ __launch_bounds__(256) void factor_gemm(
    const unsigned short* __restrict__ A,    // (4096,2048) bf16
    const unsigned short* __restrict__ Bt,   // (Hn,128,64) bf16
    unsigned short* __restrict__ Out, int coloff, int Hn, float scale)
{
  __shared__ unsigned short As[128*64];
  __shared__ unsigned short Bs[128*64];
  const int tid = threadIdx.x;
  const int mb = blockIdx.x;     // 0..31
  const int h  = blockIdx.y;     // 0..Hn-1
  const int w = tid >> 6, lane = tid & 63;
  const int wr = w >> 1, wc = w & 1;
  const int l16 = lane & 15, lg = lane >> 4;

  const int srow = tid >> 3;
  const int scol = (tid & 7) << 3;

  const unsigned short* Ap = A + (size_t)(mb*128)*2048 + coloff + h*64;
  const unsigned short* Bp = Bt + (size_t)h*(128*64);

  #pragma unroll
  for (int c = 0; c < 4; c++){
    int r = srow + 32*c;
    int idx = (r*64 + scol) ^ ((r & 7) << 3);
    *reinterpret_cast<bf16x8*>(&As[idx]) = *reinterpret_cast<const bf16x8*>(Ap + (size_t)r*2048 + scol);
    *reinterpret_cast<bf16x8*>(&Bs[idx]) = *reinterpret_cast<const bf16x8*>(Bp + r*64 + scol);
  }
  __syncthreads();

  f32x4 acc[4][4] = {};
  #pragma unroll
  for (int t = 0; t < 2; t++){
    bf16x8 af[4], bf[4];
    #pragma unroll
    for (int i = 0; i < 4; i++){
      int rowA = wr*64 + i*16 + l16;
      int col  = t*32 + lg*8;
      af[i] = *reinterpret_cast<const bf16x8*>(&As[(rowA*64 + col) ^ ((rowA & 7) << 3)]);
      int rowB = wc*64 + i*16 + l16;
      bf[i] = *reinterpret_cast<const bf16x8*>(&Bs[(rowB*64 + col) ^ ((rowB & 7) << 3)]);
    }
    #pragma unroll
    for (int i = 0; i < 4; i++)
      #pragma unroll
      for (int j = 0; j < 4; j++)
        acc[i][j] = MFMA_16x16x32(af[i], bf[j], acc[i][j]);
  }

  #pragma unroll
  for (int i = 0; i < 4; i++){
    #pragma unroll
    for (int j = 0; j < 4; j++){
      int row0 = mb*128 + wr*64 + i*16 + lg*4;
      int d    = wc*64 + j*16 + l16;
      #pragma unroll
      for (int r = 0; r < 4; r++){
        int row = row0 + r;
        int b = row >> 11, s = row & 2047;
        Out[((size_t)(b*Hn + h)*2048 + s)*128 + d] = f2b(acc[i][j][r] * scale);
      }
    }
  }
}

// ---------------- flash attention (causal, GQA 2:1), 2-phase pipelined ----------------
// grid (32 qb, 16 h, 2 b); 4 waves x 16 q-rows; KV block = 64.
// K staged via global_load_lds with inverse-XOR pre-swizzled SOURCE (T21) -> swizzled ds_read_b128.
// V staged linear via global_load_lds, transposed LDS->reg->LDS with packed b64 writes during QK phase.
// STAGE(kb+1) issued after mid barrier: in flight only during PV; __syncthreads drains are exactly needed.

__device__ __forceinline__ int vt_idx(int d, int kv){
  return d*64 + ((((kv >> 3) + d + (d >> 3)) & 7) << 3) + (kv & 7);
}

__global__ __launch_bounds__(256) void flash_attn(
    const unsigned short* __restrict__ Q,   // (B,16,2048,128) roped, pre-scaled
    const unsigned short* __restrict__ Kb,  // (B,8,2048,128) roped, /RK
    const unsigned short* __restrict__ Vb,  // (B,8,2048,128) /RV
    unsigned short* __restrict__ O)         // (B*2048, 2048)
{
  __shared__ unsigned short Ks[64*128];     // swizzled content
  __shared__ unsigned short Vrow[64*128];   // linear row-major
  __shared__ unsigned short Vt[128*64];     // vt_idx layout
  __shared__ unsigned short Pl[4][16*64];

  const int tid = threadIdx.x;
  const int w = tid >> 6, lane = tid & 63;
  const int l16 = lane & 15, lg = lane >> 4;
  const int qb = (int)gridDim.x - 1 - blockIdx.x;   // reverse: heavy blocks first
  const int h = blockIdx.y, b = blockIdx.z;
  const int hkv = h >> 1;

  const size_t qbase  = (((size_t)(b*16 + h))*2048 + qb*64 + w*16)*128;
  const size_t kvbase = ((size_t)(b*8 + hkv))*2048*128;

  // staging geometry: wave w stages rows [w*16, w*16+16); instr i covers 4 rows.
  const int sR = w*16 + (lane >> 4);     // + i*4
  const int sC = (lane & 15) * 8;

  bf16x8 aq[4];
  #pragma unroll
  for (int t = 0; t < 4; t++)
    aq[t] = *reinterpret_cast<const bf16x8*>(&Q[qbase + (size_t)l16*128 + t*32 + lg*8]);

  f32x4 oac[8] = {};
  float mrow[4], lrow[4];
  #pragma unroll
  for (int r = 0; r < 4; r++){ mrow[r] = -1e30f; lrow[r] = 0.f; }
  const int qrow0 = qb*64 + w*16 + lg*4;

  auto stage = [&](int kb){
    #pragma unroll
    for (int i = 0; i < 4; i++){
      int R = sR + i*4;
      const unsigned short* gk = Kb + kvbase + (size_t)(kb*64 + R)*128 + (sC ^ ((R & 7) << 3));
      gload_lds16(gk, &Ks[(w*16 + i*4)*128]);
      const unsigned short* gv = Vb + kvbase + (size_t)(kb*64 + R)*128 + sC;
      gload_lds16(gv, &Vrow[(w*16 + i*4)*128]);
    }
  };

  stage(0);
  __syncthreads();   // drains vmcnt(0): tile 0 resident

  const int tkv0 = (tid >> 4) * 4;   // transpose: thread handles 4 kv x 8 d
  const int td0  = (tid & 15) * 8;

  for (int kb = 0; kb <= qb; kb++){
    // --- load V sub-block for transpose (independent of QK chain) ---
    bf16x8 vr0 = *reinterpret_cast<const bf16x8*>(&Vrow[(tkv0 + 0)*128 + td0]);
    bf16x8 vr1 = *reinterpret_cast<const bf16x8*>(&Vrow[(tkv0 + 1)*128 + td0]);
    bf16x8 vr2 = *reinterpret_cast<const bf16x8*>(&Vrow[(tkv0 + 2)*128 + td0]);
    bf16x8 vr3 = *reinterpret_cast<const bf16x8*>(&Vrow[(tkv0 + 3)*128 + td0]);

    // --- S (16q x 64k) = Q @ K^T ---
    f32x4 sac[4] = {};
    #pragma unroll
    for (int nt = 0; nt < 4; nt++){
      #pragma unroll
      for (int t = 0; t < 4; t++){
        int rowK = nt*16 + l16;
        int col  = t*32 + lg*8;
        bf16x8 bk = *reinterpret_cast<const bf16x8*>(&Ks[(rowK*128 + col) ^ ((rowK & 7) << 3)]);
        sac[nt] = MFMA_16x16x32(aq[t], bk, sac[nt]);
      }
    }

    // --- write transposed V: 8x packed b64 ---
    #pragma unroll
    for (int j = 0; j < 8; j++){
      unsigned int lo = (unsigned int)(unsigned short)vr0[j] | ((unsigned int)(unsigned short)vr1[j] << 16);
      unsigned int hi = (unsigned int)(unsigned short)vr2[j] | ((unsigned int)(unsigned short)vr3[j] << 16);
      uint2 u; u.x = lo; u.y = hi;
      *reinterpret_cast<uint2*>(&Vt[vt_idx(td0 + j, tkv0)]) = u;
    }

    if (kb == qb){
      #pragma unroll
      for (int nt = 0; nt < 4; nt++){
        int kcol = kb*64 + nt*16 + l16;
        #pragma unroll
        for (int r = 0; r < 4; r++)
          if (kcol > qrow0 + r) sac[nt][r] = -1e30f;
      }
    }
    // --- online softmax ---
    float corr[4];
    #pragma unroll
    for (int r = 0; r < 4; r++){
      float v = fmaxf(fmaxf(sac[0][r], sac[1][r]), fmaxf(sac[2][r], sac[3][r]));
      v = fmaxf(v, __shfl_xor(v, 1));
      v = fmaxf(v, __shfl_xor(v, 2));
      v = fmaxf(v, __shfl_xor(v, 4));
      v = fmaxf(v, __shfl_xor(v, 8));
      float mn = fmaxf(mrow[r], v);
      corr[r] = __expf(mrow[r] - mn);
      mrow[r] = mn;
    }
    float rs[4] = {0.f, 0.f, 0.f, 0.f};
    #pragma unroll
    for (int nt = 0; nt < 4; nt++){
      #pragma unroll
      for (int r = 0; r < 4; r++){
        float p = __expf(sac[nt][r] - mrow[r]);
        sac[nt][r] = p;
        rs[r] += p;
      }
    }
    #pragma unroll
    for (int r = 0; r < 4; r++){
      float v = rs[r];
      v += __shfl_xor(v, 1); v += __shfl_xor(v, 2); v += __shfl_xor(v, 4); v += __shfl_xor(v, 8);
      lrow[r] = lrow[r]*corr[r] + v;
    }
    #pragma unroll
    for (int dn = 0; dn < 8; dn++)
      #pragma unroll
      for (int r = 0; r < 4; r++) oac[dn][r] *= corr[r];

    // --- P -> LDS (wave-private) ---
    #pragma unroll
    for (int nt = 0; nt < 4; nt++){
      #pragma unroll
      for (int r = 0; r < 4; r++){
        int row = lg*4 + r, col = nt*16 + l16;
        Pl[w][(row*64 + col) ^ ((row & 7) << 3)] = f2b(sac[nt][r]);
      }
    }

    __syncthreads();              // barrier B: Vt (+K-reads done) visible; no vmem in flight
    if (kb < qb) stage(kb + 1);   // prefetch in flight only during PV

    // --- PV ---
    #pragma unroll
    for (int t = 0; t < 2; t++){
      int colp = t*32 + lg*8;
      bf16x8 ap = *reinterpret_cast<const bf16x8*>(&Pl[w][(l16*64 + colp) ^ ((l16 & 7) << 3)]);
      #pragma unroll
      for (int dn = 0; dn < 8; dn++){
        int rowV = dn*16 + l16;
        bf16x8 bv = *reinterpret_cast<const bf16x8*>(&Vt[vt_idx(rowV, colp)]);
        oac[dn] = MFMA_16x16x32(ap, bv, oac[dn]);
      }
    }
    __syncthreads();              // barrier A: drains stage(kb+1); all reads of Ks/Vrow/Vt done
  }

  #pragma unroll
  for (int dn = 0; dn < 8; dn++){
    #pragma unroll
    for (int r = 0; r < 4; r++){
      int row = qb*64 + w*16 + lg*4 + r;
      O[((size_t)(b*2048 + row))*2048 + h*128 + dn*16 + l16] = f2b(oac[dn][r] / lrow[r]);
    }
  }
}

// ---------------- launcher ----------------

extern "C" void kernel_launch(void* const* d_in, const int* in_sizes, int n_in,
                              void* d_out, int out_size, void* d_ws, size_t ws_size,
                              hipStream_t stream)
{
  if (n_in < 10) return;
  const float* hidden = (const float*)d_in[0];
  const float* WAq = (const float*)d_in[1];
  const float* WAk = (const float*)d_in[2];
  const float* WAv = (const float*)d_in[3];
  const float* Bq  = (const float*)d_in[4];
  const float* Bk  = (const float*)d_in[5];
  const float* Bv  = (const float*)d_in[6];
  const float* Wo  = (const float*)d_in[7];
  const float* fcos = (const float*)d_in[8];
  const float* fsin = (const float*)d_in[9];
  float* out = (float*)d_out;

  char* p = (char*)d_ws;
  auto take = [&](size_t bytes){ char* q = p; p += (bytes + 255) & ~(size_t)255; return q; };
  unsigned short* Xb   = (unsigned short*)take((size_t)4096*2048*2);
  unsigned short* Wqkv = (unsigned short*)take((size_t)2048*2048*2);
  unsigned short* Wob  = (unsigned short*)take((size_t)2048*2048*2);
  unsigned short* Aqkv = (unsigned short*)take((size_t)4096*2048*2);
  unsigned short* Bqt  = (unsigned short*)take((size_t)16*128*64*2);
  unsigned short* Bkt  = (unsigned short*)take((size_t)8*128*64*2);
  unsigned short* Bvt  = (unsigned short*)take((size_t)8*128*64*2);
  unsigned short* qbuf = (unsigned short*)take((size_t)2*16*2048*128*2);
  unsigned short* kbuf = (unsigned short*)take((size_t)2*8*2048*128*2);
  unsigned short* vbuf = (unsigned short*)take((size_t)2*8*2048*128*2);
  unsigned short* aout = (unsigned short*)take((size_t)4096*2048*2);
  if ((size_t)(p - (char*)d_ws) > ws_size) return;

  auto cvt = [&](const float* s, unsigned short* d, size_t n){
    int n4 = (int)(n >> 2);
    int blocks = (n4 + 255) / 256; if (blocks > 4096) blocks = 4096;
    cvt_f32_bf16<<<blocks, 256, 0, stream>>>(s, d, n4);
  };
  cvt(hidden, Xb, (size_t)4096*2048);
  cvt(WAq, Wqkv,                       (size_t)1024*2048);
  cvt(WAk, Wqkv + (size_t)1024*2048,   (size_t)512*2048);
  cvt(WAv, Wqkv + (size_t)1536*2048,   (size_t)512*2048);
  cvt(Wo,  Wob, (size_t)2048*2048);
  cvt_factor_t<<<(16*64*128)/256, 256, 0, stream>>>(Bq, Bqt, 16*64*128);
  cvt_factor_t<<<(8*64*128)/256, 256, 0, stream>>>(Bk, Bkt, 8*64*128);
  cvt_factor_t<<<(8*64*128)/256, 256, 0, stream>>>(Bv, Bvt, 8*64*128);

  // A-factors: (4096,2048) = Xb @ Wqkv^T
  gemm_bt<0><<<dim3(32,16), 256, 0, stream>>>(Xb, Wqkv, (void*)Aqkv, 2048, 2048, 1.0f);

  const float SCALE = 0.08838834764831845f;  // 128^-0.5
  factor_gemm<<<dim3(32,16), 256, 0, stream>>>(Aqkv, Bqt, qbuf, 0,    16, SCALE/64.0f);
  factor_gemm<<<dim3(32,8),  256, 0, stream>>>(Aqkv, Bkt, kbuf, 1024, 8,  1.0f/64.0f);
  factor_gemm<<<dim3(32,8),  256, 0, stream>>>(Aqkv, Bvt, vbuf, 1536, 8,  1.0f/64.0f);

  rope_inplace<<<(32*2048*16)/256, 256, 0, stream>>>(qbuf, fcos, fsin, 32*2048*16);
  rope_inplace<<<(16*2048*16)/256, 256, 0, stream>>>(kbuf, fcos, fsin, 16*2048*16);

  flash_attn<<<dim3(32,16,2), 256, 0, stream>>>(qbuf, kbuf, vbuf, aout);

  // final: (4096,2048) fp32 = aout @ Wo^T
  gemm_bt<1><<<dim3(32,16), 256, 0, stream>>>(aout, Wob, (void*)out, 2048, 2048, 1.0f);
}

// Round 5
// 391.745 us; speedup vs baseline: 1.9279x; 1.2659x over previous
//
#include <hip/hip_runtime.h>
#include <hip/hip_bf16.h>

typedef __attribute__((ext_vector_type(8))) short bf16x8;
typedef __attribute__((ext_vector_type(4))) float f32x4;

#define MFMA_16x16x32(a,b,c) __builtin_amdgcn_mfma_f32_16x16x32_bf16((a),(b),(c),0,0,0)

__device__ __forceinline__ unsigned short f2b(float f){
  unsigned int u = __builtin_bit_cast(unsigned int, f);
  u = u + 0x7FFFu + ((u >> 16) & 1u);
  return (unsigned short)(u >> 16);
}
__device__ __forceinline__ float b2f(unsigned short h){
  unsigned int u = ((unsigned int)h) << 16;
  return __builtin_bit_cast(float, u);
}

__device__ __forceinline__ void gload_lds16(const unsigned short* g, unsigned short* l){
  __builtin_amdgcn_global_load_lds(
      (const __attribute__((address_space(1))) void*)g,
      (__attribute__((address_space(3))) void*)l, 16, 0, 0);
}

// ---------------- elementwise converters ----------------

__global__ void cvt_f32_bf16(const float* __restrict__ src, unsigned short* __restrict__ dst, int n4){
  int i = blockIdx.x * blockDim.x + threadIdx.x;
  int stride = gridDim.x * blockDim.x;
  for (; i < n4; i += stride){
    float4 v = reinterpret_cast<const float4*>(src)[i];
    ushort4 o;
    o.x = f2b(v.x); o.y = f2b(v.y); o.z = f2b(v.z); o.w = f2b(v.w);
    reinterpret_cast<ushort4*>(dst)[i] = o;
  }
}

// src (Hn,64,128) f32 -> dst (Hn,128,64) bf16 (transpose r<->d per head)
__global__ void cvt_factor_t(const float* __restrict__ src, unsigned short* __restrict__ dst, int n){
  int i = blockIdx.x * blockDim.x + threadIdx.x;
  if (i >= n) return;
  int d = i & 127, r = (i >> 7) & 63, h = i >> 13;
  dst[(h << 13) + (d << 6) + r] = f2b(src[i]);
}

// in-place RoPE on (BH,2048,128) bf16; fc/fs are (2048,64) f32
__global__ void rope_inplace(unsigned short* __restrict__ buf,
                             const float* __restrict__ fc,
                             const float* __restrict__ fs, int total){
  int i = blockIdx.x * blockDim.x + threadIdx.x;
  if (i >= total) return;
  int d4 = (i & 15) << 2;           // 0,4,...,60
  int s  = (i >> 4) & 2047;
  size_t base = ((size_t)(i >> 4)) * 128;   // (bh*2048+s)*128
  ushort4 x1 = *reinterpret_cast<ushort4*>(buf + base + d4);
  ushort4 x2 = *reinterpret_cast<ushort4*>(buf + base + 64 + d4);
  float4 c  = *reinterpret_cast<const float4*>(fc + (size_t)s*64 + d4);
  float4 sn = *reinterpret_cast<const float4*>(fs + (size_t)s*64 + d4);
  ushort4 o1, o2; float a, b;
  a = b2f(x1.x); b = b2f(x2.x); o1.x = f2b(a*c.x - b*sn.x); o2.x = f2b(a*sn.x + b*c.x);
  a = b2f(x1.y); b = b2f(x2.y); o1.y = f2b(a*c.y - b*sn.y); o2.y = f2b(a*sn.y + b*c.y);
  a = b2f(x1.z); b = b2f(x2.z); o1.z = f2b(a*c.z - b*sn.z); o2.z = f2b(a*sn.z + b*c.z);
  a = b2f(x1.w); b = b2f(x2.w); o1.w = f2b(a*c.w - b*sn.w); o2.w = f2b(a*sn.w + b*c.w);
  *reinterpret_cast<ushort4*>(buf + base + d4)      = o1;
  *reinterpret_cast<ushort4*>(buf + base + 64 + d4) = o2;
}

// ---------------- big GEMM-BT: C(MxN) = A(MxK) @ B(NxK)^T, bf16 in ----------------

template<int OUT_F32>
__global__ __launch_bounds__(256) void gemm_bt(
    const unsigned short* __restrict__ A, const unsigned short* __restrict__ B,
    void* __restrict__ Cv, int N, int K, float scale)
{
  __shared__ unsigned short As[128*64];
  __shared__ unsigned short Bs[128*64];
  const int tid = threadIdx.x;
  const int mb = blockIdx.x, nb = blockIdx.y;
  const int w = tid >> 6, lane = tid & 63;
  const int wr = w >> 1, wc = w & 1;
  const int l16 = lane & 15, lg = lane >> 4;

  f32x4 acc[4][4] = {};

  const int srow = tid >> 3;          // 0..31
  const int scol = (tid & 7) << 3;    // 0..56

  const unsigned short* Ap = A + (size_t)(mb*128)*K;
  const unsigned short* Bp = B + (size_t)(nb*128)*K;

  bf16x8 ar[4], br[4];
  #pragma unroll
  for (int c = 0; c < 4; c++){
    ar[c] = *reinterpret_cast<const bf16x8*>(Ap + (size_t)(srow + 32*c)*K + scol);
    br[c] = *reinterpret_cast<const bf16x8*>(Bp + (size_t)(srow + 32*c)*K + scol);
  }
  const int nkt = K >> 6;
  for (int kt = 0; kt < nkt; kt++){
    __syncthreads();
    #pragma unroll
    for (int c = 0; c < 4; c++){
      int r = srow + 32*c;
      int idx = (r*64 + scol) ^ ((r & 7) << 3);
      *reinterpret_cast<bf16x8*>(&As[idx]) = ar[c];
      *reinterpret_cast<bf16x8*>(&Bs[idx]) = br[c];
    }
    __syncthreads();
    if (kt + 1 < nkt){
      const unsigned short* Ap2 = Ap + (size_t)(kt+1)*64;
      const unsigned short* Bp2 = Bp + (size_t)(kt+1)*64;
      #pragma unroll
      for (int c = 0; c < 4; c++){
        ar[c] = *reinterpret_cast<const bf16x8*>(Ap2 + (size_t)(srow + 32*c)*K + scol);
        br[c] = *reinterpret_cast<const bf16x8*>(Bp2 + (size_t)(srow + 32*c)*K + scol);
      }
    }
    #pragma unroll
    for (int t = 0; t < 2; t++){
      bf16x8 af[4], bf[4];
      #pragma unroll
      for (int i = 0; i < 4; i++){
        int rowA = wr*64 + i*16 + l16;
        int col  = t*32 + lg*8;
        af[i] = *reinterpret_cast<const bf16x8*>(&As[(rowA*64 + col) ^ ((rowA & 7) << 3)]);
        int rowB = wc*64 + i*16 + l16;
        bf[i] = *reinterpret_cast<const bf16x8*>(&Bs[(rowB*64 + col) ^ ((rowB & 7) << 3)]);
      }
      #pragma unroll
      for (int i = 0; i < 4; i++)
        #pragma unroll
        for (int j = 0; j < 4; j++)
          acc[i][j] = MFMA_16x16x32(af[i], bf[j], acc[i][j]);
    }
  }
  #pragma unroll
  for (int i = 0; i < 4; i++){
    #pragma unroll
    for (int j = 0; j < 4; j++){
      int row = mb*128 + wr*64 + i*16 + lg*4;
      int col = nb*128 + wc*64 + j*16 + l16;
      #pragma unroll
      for (int r = 0; r < 4; r++){
        float v = acc[i][j][r] * scale;
        if (OUT_F32) reinterpret_cast<float*>(Cv)[(size_t)(row + r)*N + col] = v;
        else reinterpret_cast<unsigned short*>(Cv)[(size_t)(row + r)*N + col] = f2b(v);
      }
    }
  }
}

// ---------------- factor GEMM ----------------

__global__ __launch_bounds__(256) void factor_gemm(
    const unsigned short* __restrict__ A,    // (4096,2048) bf16
    const unsigned short* __restrict__ Bt,   // (Hn,128,64) bf16
    unsigned short* __restrict__ Out, int coloff, int Hn, float scale)
{
  __shared__ unsigned short As[128*64];
  __shared__ unsigned short Bs[128*64];
  const int tid = threadIdx.x;
  const int mb = blockIdx.x;     // 0..31
  const int h  = blockIdx.y;     // 0..Hn-1
  const int w = tid >> 6, lane = tid & 63;
  const int wr = w >> 1, wc = w & 1;
  const int l16 = lane & 15, lg = lane >> 4;

  const int srow = tid >> 3;
  const int scol = (tid & 7) << 3;

  const unsigned short* Ap = A + (size_t)(mb*128)*2048 + coloff + h*64;
  const unsigned short* Bp = Bt + (size_t)h*(128*64);

  #pragma unroll
  for (int c = 0; c < 4; c++){
    int r = srow + 32*c;
    int idx = (r*64 + scol) ^ ((r & 7) << 3);
    *reinterpret_cast<bf16x8*>(&As[idx]) = *reinterpret_cast<const bf16x8*>(Ap + (size_t)r*2048 + scol);
    *reinterpret_cast<bf16x8*>(&Bs[idx]) = *reinterpret_cast<const bf16x8*>(Bp + r*64 + scol);
  }
  __syncthreads();

  f32x4 acc[4][4] = {};
  #pragma unroll
  for (int t = 0; t < 2; t++){
    bf16x8 af[4], bf[4];
    #pragma unroll
    for (int i = 0; i < 4; i++){
      int rowA = wr*64 + i*16 + l16;
      int col  = t*32 + lg*8;
      af[i] = *reinterpret_cast<const bf16x8*>(&As[(rowA*64 + col) ^ ((rowA & 7) << 3)]);
      int rowB = wc*64 + i*16 + l16;
      bf[i] = *reinterpret_cast<const bf16x8*>(&Bs[(rowB*64 + col) ^ ((rowB & 7) << 3)]);
    }
    #pragma unroll
    for (int i = 0; i < 4; i++)
      #pragma unroll
      for (int j = 0; j < 4; j++)
        acc[i][j] = MFMA_16x16x32(af[i], bf[j], acc[i][j]);
  }

  #pragma unroll
  for (int i = 0; i < 4; i++){
    #pragma unroll
    for (int j = 0; j < 4; j++){
      int row0 = mb*128 + wr*64 + i*16 + lg*4;
      int d    = wc*64 + j*16 + l16;
      #pragma unroll
      for (int r = 0; r < 4; r++){
        int row = row0 + r;
        int b = row >> 11, s = row & 2047;
        Out[((size_t)(b*Hn + h)*2048 + s)*128 + d] = f2b(acc[i][j][r] * scale);
      }
    }
  }
}

// ---------------- flash attention (causal, GQA 2:1), 2-phase pipelined, PAIRED q-tiles ----------------
// grid (16 pair, 16 h, 2 b); block handles q-tiles {qb, 31-qb} sequentially over the same K/V
// stream => every block does exactly 33 stage-iterations (perfect load balance; 512 blocks =
// exactly 2 blocks/CU capacity at 57KB LDS). Prefetch chain continues across the phase boundary.

__device__ __forceinline__ int vt_idx(int d, int kv){
  return d*64 + ((((kv >> 3) + d + (d >> 3)) & 7) << 3) + (kv & 7);
}

__global__ __launch_bounds__(256) void flash_attn(
    const unsigned short* __restrict__ Q,   // (B,16,2048,128) roped, pre-scaled
    const unsigned short* __restrict__ Kb,  // (B,8,2048,128) roped, /RK
    const unsigned short* __restrict__ Vb,  // (B,8,2048,128) /RV
    unsigned short* __restrict__ O)         // (B*2048, 2048)
{
  __shared__ unsigned short Ks[64*128];     // swizzled content
  __shared__ unsigned short Vrow[64*128];   // linear row-major
  __shared__ unsigned short Vt[128*64];     // vt_idx layout
  __shared__ unsigned short Pl[4][16*64];

  const int tid = threadIdx.x;
  const int w = tid >> 6, lane = tid & 63;
  const int l16 = lane & 15, lg = lane >> 4;
  const int h = blockIdx.y, b = blockIdx.z;
  const int hkv = h >> 1;

  const size_t hbase  = ((size_t)(b*16 + h))*2048*128;
  const size_t kvbase = ((size_t)(b*8 + hkv))*2048*128;

  // staging geometry: wave w stages rows [w*16, w*16+16); instr i covers 4 rows.
  const int sR = w*16 + (lane >> 4);     // + i*4
  const int sC = (lane & 15) * 8;

  auto stage = [&](int kb){
    #pragma unroll
    for (int i = 0; i < 4; i++){
      int R = sR + i*4;
      const unsigned short* gk = Kb + kvbase + (size_t)(kb*64 + R)*128 + (sC ^ ((R & 7) << 3));
      gload_lds16(gk, &Ks[(w*16 + i*4)*128]);
      const unsigned short* gv = Vb + kvbase + (size_t)(kb*64 + R)*128 + sC;
      gload_lds16(gv, &Vrow[(w*16 + i*4)*128]);
    }
  };

  stage(0);
  __syncthreads();   // tile 0 resident

  const int tkv0 = (tid >> 4) * 4;   // transpose: thread handles 4 kv x 8 d
  const int td0  = (tid & 15) * 8;

  const int qtiles[2] = { (int)blockIdx.x, 31 - (int)blockIdx.x };

  for (int ph = 0; ph < 2; ph++){
    const int qe = qtiles[ph];
    const size_t qbase = hbase + (size_t)(qe*64 + w*16)*128;
    const int qrow0 = qe*64 + w*16 + lg*4;

    bf16x8 aq[4];
    #pragma unroll
    for (int t = 0; t < 4; t++)
      aq[t] = *reinterpret_cast<const bf16x8*>(&Q[qbase + (size_t)l16*128 + t*32 + lg*8]);

    f32x4 oac[8] = {};
    float mrow[4], lrow[4];
    #pragma unroll
    for (int r = 0; r < 4; r++){ mrow[r] = -1e30f; lrow[r] = 0.f; }

    for (int kb = 0; kb <= qe; kb++){
      // --- load V sub-block for transpose (independent of QK chain) ---
      bf16x8 vr0 = *reinterpret_cast<const bf16x8*>(&Vrow[(tkv0 + 0)*128 + td0]);
      bf16x8 vr1 = *reinterpret_cast<const bf16x8*>(&Vrow[(tkv0 + 1)*128 + td0]);
      bf16x8 vr2 = *reinterpret_cast<const bf16x8*>(&Vrow[(tkv0 + 2)*128 + td0]);
      bf16x8 vr3 = *reinterpret_cast<const bf16x8*>(&Vrow[(tkv0 + 3)*128 + td0]);

      // --- S (16q x 64k) = Q @ K^T ---
      f32x4 sac[4] = {};
      #pragma unroll
      for (int nt = 0; nt < 4; nt++){
        #pragma unroll
        for (int t = 0; t < 4; t++){
          int rowK = nt*16 + l16;
          int col  = t*32 + lg*8;
          bf16x8 bk = *reinterpret_cast<const bf16x8*>(&Ks[(rowK*128 + col) ^ ((rowK & 7) << 3)]);
          sac[nt] = MFMA_16x16x32(aq[t], bk, sac[nt]);
        }
      }

      // --- write transposed V: 8x packed b64 ---
      #pragma unroll
      for (int j = 0; j < 8; j++){
        unsigned int lo = (unsigned int)(unsigned short)vr0[j] | ((unsigned int)(unsigned short)vr1[j] << 16);
        unsigned int hi = (unsigned int)(unsigned short)vr2[j] | ((unsigned int)(unsigned short)vr3[j] << 16);
        uint2 u; u.x = lo; u.y = hi;
        *reinterpret_cast<uint2*>(&Vt[vt_idx(td0 + j, tkv0)]) = u;
      }

      if (kb == qe){
        #pragma unroll
        for (int nt = 0; nt < 4; nt++){
          int kcol = kb*64 + nt*16 + l16;
          #pragma unroll
          for (int r = 0; r < 4; r++)
            if (kcol > qrow0 + r) sac[nt][r] = -1e30f;
        }
      }
      // --- online softmax ---
      float corr[4];
      #pragma unroll
      for (int r = 0; r < 4; r++){
        float v = fmaxf(fmaxf(sac[0][r], sac[1][r]), fmaxf(sac[2][r], sac[3][r]));
        v = fmaxf(v, __shfl_xor(v, 1));
        v = fmaxf(v, __shfl_xor(v, 2));
        v = fmaxf(v, __shfl_xor(v, 4));
        v = fmaxf(v, __shfl_xor(v, 8));
        float mn = fmaxf(mrow[r], v);
        corr[r] = __expf(mrow[r] - mn);
        mrow[r] = mn;
      }
      float rs[4] = {0.f, 0.f, 0.f, 0.f};
      #pragma unroll
      for (int nt = 0; nt < 4; nt++){
        #pragma unroll
        for (int r = 0; r < 4; r++){
          float p = __expf(sac[nt][r] - mrow[r]);
          sac[nt][r] = p;
          rs[r] += p;
        }
      }
      #pragma unroll
      for (int r = 0; r < 4; r++){
        float v = rs[r];
        v += __shfl_xor(v, 1); v += __shfl_xor(v, 2); v += __shfl_xor(v, 4); v += __shfl_xor(v, 8);
        lrow[r] = lrow[r]*corr[r] + v;
      }
      #pragma unroll
      for (int dn = 0; dn < 8; dn++)
        #pragma unroll
        for (int r = 0; r < 4; r++) oac[dn][r] *= corr[r];

      // --- P -> LDS (wave-private) ---
      #pragma unroll
      for (int nt = 0; nt < 4; nt++){
        #pragma unroll
        for (int r = 0; r < 4; r++){
          int row = lg*4 + r, col = nt*16 + l16;
          Pl[w][(row*64 + col) ^ ((row & 7) << 3)] = f2b(sac[nt][r]);
        }
      }

      __syncthreads();              // barrier B: Vt visible; no vmem in flight
      // prefetch next step's tile (chain continues across the phase boundary)
      if (kb < qe) stage(kb + 1);
      else if (ph == 0) stage(0);

      // --- PV ---
      #pragma unroll
      for (int t = 0; t < 2; t++){
        int colp = t*32 + lg*8;
        bf16x8 ap = *reinterpret_cast<const bf16x8*>(&Pl[w][(l16*64 + colp) ^ ((l16 & 7) << 3)]);
        #pragma unroll
        for (int dn = 0; dn < 8; dn++){
          int rowV = dn*16 + l16;
          bf16x8 bv = *reinterpret_cast<const bf16x8*>(&Vt[vt_idx(rowV, colp)]);
          oac[dn] = MFMA_16x16x32(ap, bv, oac[dn]);
        }
      }
      __syncthreads();              // barrier A: drains prefetch; all LDS reads done
    }

    // epilogue for this q-tile
    #pragma unroll
    for (int dn = 0; dn < 8; dn++){
      #pragma unroll
      for (int r = 0; r < 4; r++){
        int row = qe*64 + w*16 + lg*4 + r;
        O[((size_t)(b*2048 + row))*2048 + h*128 + dn*16 + l16] = f2b(oac[dn][r] / lrow[r]);
      }
    }
  }
}

// ---------------- launcher ----------------

extern "C" void kernel_launch(void* const* d_in, const int* in_sizes, int n_in,
                              void* d_out, int out_size, void* d_ws, size_t ws_size,
                              hipStream_t stream)
{
  if (n_in < 10) return;
  const float* hidden = (const float*)d_in[0];
  const float* WAq = (const float*)d_in[1];
  const float* WAk = (const float*)d_in[2];
  const float* WAv = (const float*)d_in[3];
  const float* Bq  = (const float*)d_in[4];
  const float* Bk  = (const float*)d_in[5];
  const float* Bv  = (const float*)d_in[6];
  const float* Wo  = (const float*)d_in[7];
  const float* fcos = (const float*)d_in[8];
  const float* fsin = (const float*)d_in[9];
  float* out = (float*)d_out;

  char* p = (char*)d_ws;
  auto take = [&](size_t bytes){ char* q = p; p += (bytes + 255) & ~(size_t)255; return q; };
  unsigned short* Xb   = (unsigned short*)take((size_t)4096*2048*2);
  unsigned short* Wqkv = (unsigned short*)take((size_t)2048*2048*2);
  unsigned short* Wob  = (unsigned short*)take((size_t)2048*2048*2);
  unsigned short* Aqkv = (unsigned short*)take((size_t)4096*2048*2);
  unsigned short* Bqt  = (unsigned short*)take((size_t)16*128*64*2);
  unsigned short* Bkt  = (unsigned short*)take((size_t)8*128*64*2);
  unsigned short* Bvt  = (unsigned short*)take((size_t)8*128*64*2);
  unsigned short* qbuf = (unsigned short*)take((size_t)2*16*2048*128*2);
  unsigned short* kbuf = (unsigned short*)take((size_t)2*8*2048*128*2);
  unsigned short* vbuf = (unsigned short*)take((size_t)2*8*2048*128*2);
  unsigned short* aout = (unsigned short*)take((size_t)4096*2048*2);
  if ((size_t)(p - (char*)d_ws) > ws_size) return;

  auto cvt = [&](const float* s, unsigned short* d, size_t n){
    int n4 = (int)(n >> 2);
    int blocks = (n4 + 255) / 256; if (blocks > 4096) blocks = 4096;
    cvt_f32_bf16<<<blocks, 256, 0, stream>>>(s, d, n4);
  };
  cvt(hidden, Xb, (size_t)4096*2048);
  cvt(WAq, Wqkv,                       (size_t)1024*2048);
  cvt(WAk, Wqkv + (size_t)1024*2048,   (size_t)512*2048);
  cvt(WAv, Wqkv + (size_t)1536*2048,   (size_t)512*2048);
  cvt(Wo,  Wob, (size_t)2048*2048);
  cvt_factor_t<<<(16*64*128)/256, 256, 0, stream>>>(Bq, Bqt, 16*64*128);
  cvt_factor_t<<<(8*64*128)/256, 256, 0, stream>>>(Bk, Bkt, 8*64*128);
  cvt_factor_t<<<(8*64*128)/256, 256, 0, stream>>>(Bv, Bvt, 8*64*128);

  // A-factors: (4096,2048) = Xb @ Wqkv^T
  gemm_bt<0><<<dim3(32,16), 256, 0, stream>>>(Xb, Wqkv, (void*)Aqkv, 2048, 2048, 1.0f);

  const float SCALE = 0.08838834764831845f;  // 128^-0.5
  factor_gemm<<<dim3(32,16), 256, 0, stream>>>(Aqkv, Bqt, qbuf, 0,    16, SCALE/64.0f);
  factor_gemm<<<dim3(32,8),  256, 0, stream>>>(Aqkv, Bkt, kbuf, 1024, 8,  1.0f/64.0f);
  factor_gemm<<<dim3(32,8),  256, 0, stream>>>(Aqkv, Bvt, vbuf, 1536, 8,  1.0f/64.0f);

  rope_inplace<<<(32*2048*16)/256, 256, 0, stream>>>(qbuf, fcos, fsin, 32*2048*16);
  rope_inplace<<<(16*2048*16)/256, 256, 0, stream>>>(kbuf, fcos, fsin, 16*2048*16);

  flash_attn<<<dim3(16,16,2), 256, 0, stream>>>(qbuf, kbuf, vbuf, aout);

  // final: (4096,2048) fp32 = aout @ Wo^T
  gemm_bt<1><<<dim3(32,16), 256, 0, stream>>>(aout, Wob, (void*)out, 2048, 2048, 1.0f);
}

// Round 6
// 384.711 us; speedup vs baseline: 1.9632x; 1.0183x over previous
//
#include <hip/hip_runtime.h>
#include <hip/hip_bf16.h>

typedef __attribute__((ext_vector_type(8))) short bf16x8;
typedef __attribute__((ext_vector_type(4))) float f32x4;

#define MFMA_16x16x32(a,b,c) __builtin_amdgcn_mfma_f32_16x16x32_bf16((a),(b),(c),0,0,0)

__device__ __forceinline__ unsigned short f2b(float f){
  unsigned int u = __builtin_bit_cast(unsigned int, f);
  u = u + 0x7FFFu + ((u >> 16) & 1u);
  return (unsigned short)(u >> 16);
}
__device__ __forceinline__ float b2f(unsigned short h){
  unsigned int u = ((unsigned int)h) << 16;
  return __builtin_bit_cast(float, u);
}

__device__ __forceinline__ void gload_lds16(const unsigned short* g, unsigned short* l){
  __builtin_amdgcn_global_load_lds(
      (const __attribute__((address_space(1))) void*)g,
      (__attribute__((address_space(3))) void*)l, 16, 0, 0);
}

// ---------------- elementwise converters ----------------

__global__ void cvt_f32_bf16(const float* __restrict__ src, unsigned short* __restrict__ dst, int n4){
  int i = blockIdx.x * blockDim.x + threadIdx.x;
  int stride = gridDim.x * blockDim.x;
  for (; i < n4; i += stride){
    float4 v = reinterpret_cast<const float4*>(src)[i];
    ushort4 o;
    o.x = f2b(v.x); o.y = f2b(v.y); o.z = f2b(v.z); o.w = f2b(v.w);
    reinterpret_cast<ushort4*>(dst)[i] = o;
  }
}

// src (Hn,64,128) f32 -> dst (Hn,128,64) bf16 (transpose r<->d per head)
__global__ void cvt_factor_t(const float* __restrict__ src, unsigned short* __restrict__ dst, int n){
  int i = blockIdx.x * blockDim.x + threadIdx.x;
  if (i >= n) return;
  int d = i & 127, r = (i >> 7) & 63, h = i >> 13;
  dst[(h << 13) + (d << 6) + r] = f2b(src[i]);
}

// in-place RoPE on (BH,2048,128) bf16; fc/fs are (2048,64) f32
__global__ void rope_inplace(unsigned short* __restrict__ buf,
                             const float* __restrict__ fc,
                             const float* __restrict__ fs, int total){
  int i = blockIdx.x * blockDim.x + threadIdx.x;
  if (i >= total) return;
  int d4 = (i & 15) << 2;           // 0,4,...,60
  int s  = (i >> 4) & 2047;
  size_t base = ((size_t)(i >> 4)) * 128;   // (bh*2048+s)*128
  ushort4 x1 = *reinterpret_cast<ushort4*>(buf + base + d4);
  ushort4 x2 = *reinterpret_cast<ushort4*>(buf + base + 64 + d4);
  float4 c  = *reinterpret_cast<const float4*>(fc + (size_t)s*64 + d4);
  float4 sn = *reinterpret_cast<const float4*>(fs + (size_t)s*64 + d4);
  ushort4 o1, o2; float a, b;
  a = b2f(x1.x); b = b2f(x2.x); o1.x = f2b(a*c.x - b*sn.x); o2.x = f2b(a*sn.x + b*c.x);
  a = b2f(x1.y); b = b2f(x2.y); o1.y = f2b(a*c.y - b*sn.y); o2.y = f2b(a*sn.y + b*c.y);
  a = b2f(x1.z); b = b2f(x2.z); o1.z = f2b(a*c.z - b*sn.z); o2.z = f2b(a*sn.z + b*c.z);
  a = b2f(x1.w); b = b2f(x2.w); o1.w = f2b(a*c.w - b*sn.w); o2.w = f2b(a*sn.w + b*c.w);
  *reinterpret_cast<ushort4*>(buf + base + d4)      = o1;
  *reinterpret_cast<ushort4*>(buf + base + 64 + d4) = o2;
}

// ---------------- big GEMM-BT: C(MxN) = A(MxK) @ B(NxK)^T, bf16 in ----------------
// m97-style: global_load_lds width-16 staging (T21 pre-swizzled source), double-buffered
// LDS, T3-minimal 2-phase: stage(next) issued BEFORE compute, ONE barrier per K-step.

template<int OUT_F32>
__global__ __launch_bounds__(256) void gemm_bt(
    const unsigned short* __restrict__ A, const unsigned short* __restrict__ B,
    void* __restrict__ Cv, int N, int K, float scale)
{
  __shared__ unsigned short As[2][128*64];
  __shared__ unsigned short Bs[2][128*64];
  const int tid = threadIdx.x;
  const int mb = blockIdx.x, nb = blockIdx.y;
  const int w = tid >> 6, lane = tid & 63;
  const int wr = w >> 1, wc = w & 1;
  const int l16 = lane & 15, lg = lane >> 4;

  f32x4 acc[4][4] = {};

  const unsigned short* Ap = A + (size_t)(mb*128)*K;
  const unsigned short* Bp = B + (size_t)(nb*128)*K;

  // staging geometry (per wave, 4 instrs each for A and B):
  //   instr i stages 8 rows: r = 32w + 8i + (lane>>3), linear LDS dest = 2048w + 512i (+lane*8 by HW)
  //   logical col pre-swizzled: c = ((lane&7) ^ (lane>>3))*8  (since r&7 == lane>>3)
  const int sRo = 32*w + (lane >> 3);           // + 8i
  const int sCo = ((lane & 7) ^ (lane >> 3)) << 3;
  const int ldsW = 2048*w;                      // + 512i

  auto stage = [&](int kt, int buf){
    const unsigned short* Ak = Ap + (size_t)kt*64 + sCo;
    const unsigned short* Bk = Bp + (size_t)kt*64 + sCo;
    #pragma unroll
    for (int i = 0; i < 4; i++)
      gload_lds16(Ak + (size_t)(sRo + 8*i)*K, &As[buf][ldsW + 512*i]);
    #pragma unroll
    for (int i = 0; i < 4; i++)
      gload_lds16(Bk + (size_t)(sRo + 8*i)*K, &Bs[buf][ldsW + 512*i]);
  };

  const int nkt = K >> 6;
  stage(0, 0);
  __syncthreads();            // drains vmcnt(0): tile 0 resident

  int cur = 0;
  for (int kt = 0; kt < nkt; kt++){
    if (kt + 1 < nkt) stage(kt + 1, cur ^ 1);   // in flight during compute
    #pragma unroll
    for (int t = 0; t < 2; t++){
      bf16x8 af[4], bf[4];
      #pragma unroll
      for (int i = 0; i < 4; i++){
        int rowA = wr*64 + i*16 + l16;
        int col  = t*32 + lg*8;
        af[i] = *reinterpret_cast<const bf16x8*>(&As[cur][(rowA*64 + col) ^ ((rowA & 7) << 3)]);
        int rowB = wc*64 + i*16 + l16;
        bf[i] = *reinterpret_cast<const bf16x8*>(&Bs[cur][(rowB*64 + col) ^ ((rowB & 7) << 3)]);
      }
      #pragma unroll
      for (int i = 0; i < 4; i++)
        #pragma unroll
        for (int j = 0; j < 4; j++)
          acc[i][j] = MFMA_16x16x32(af[i], bf[j], acc[i][j]);
    }
    __syncthreads();          // one barrier/K-step: drains prefetch, fences LDS reuse
    cur ^= 1;
  }

  #pragma unroll
  for (int i = 0; i < 4; i++){
    #pragma unroll
    for (int j = 0; j < 4; j++){
      int row = mb*128 + wr*64 + i*16 + lg*4;
      int col = nb*128 + wc*64 + j*16 + l16;
      #pragma unroll
      for (int r = 0; r < 4; r++){
        float v = acc[i][j][r] * scale;
        if (OUT_F32) reinterpret_cast<float*>(Cv)[(size_t)(row + r)*N + col] = v;
        else reinterpret_cast<unsigned short*>(Cv)[(size_t)(row + r)*N + col] = f2b(v);
      }
    }
  }
}

// ---------------- factor GEMM ----------------

__global__ __launch_bounds__(256) void factor_gemm(
    const unsigned short* __restrict__ A,    // (4096,2048) bf16
    const unsigned short* __restrict__ Bt,   // (Hn,128,64) bf16
    unsigned short* __restrict__ Out, int coloff, int Hn, float scale)
{
  __shared__ unsigned short As[128*64];
  __shared__ unsigned short Bs[128*64];
  const int tid = threadIdx.x;
  const int mb = blockIdx.x;     // 0..31
  const int h  = blockIdx.y;     // 0..Hn-1
  const int w = tid >> 6, lane = tid & 63;
  const int wr = w >> 1, wc = w & 1;
  const int l16 = lane & 15, lg = lane >> 4;

  const int srow = tid >> 3;
  const int scol = (tid & 7) << 3;

  const unsigned short* Ap = A + (size_t)(mb*128)*2048 + coloff + h*64;
  const unsigned short* Bp = Bt + (size_t)h*(128*64);

  #pragma unroll
  for (int c = 0; c < 4; c++){
    int r = srow + 32*c;
    int idx = (r*64 + scol) ^ ((r & 7) << 3);
    *reinterpret_cast<bf16x8*>(&As[idx]) = *reinterpret_cast<const bf16x8*>(Ap + (size_t)r*2048 + scol);
    *reinterpret_cast<bf16x8*>(&Bs[idx]) = *reinterpret_cast<const bf16x8*>(Bp + r*64 + scol);
  }
  __syncthreads();

  f32x4 acc[4][4] = {};
  #pragma unroll
  for (int t = 0; t < 2; t++){
    bf16x8 af[4], bf[4];
    #pragma unroll
    for (int i = 0; i < 4; i++){
      int rowA = wr*64 + i*16 + l16;
      int col  = t*32 + lg*8;
      af[i] = *reinterpret_cast<const bf16x8*>(&As[(rowA*64 + col) ^ ((rowA & 7) << 3)]);
      int rowB = wc*64 + i*16 + l16;
      bf[i] = *reinterpret_cast<const bf16x8*>(&Bs[(rowB*64 + col) ^ ((rowB & 7) << 3)]);
    }
    #pragma unroll
    for (int i = 0; i < 4; i++)
      #pragma unroll
      for (int j = 0; j < 4; j++)
        acc[i][j] = MFMA_16x16x32(af[i], bf[j], acc[i][j]);
  }

  #pragma unroll
  for (int i = 0; i < 4; i++){
    #pragma unroll
    for (int j = 0; j < 4; j++){
      int row0 = mb*128 + wr*64 + i*16 + lg*4;
      int d    = wc*64 + j*16 + l16;
      #pragma unroll
      for (int r = 0; r < 4; r++){
        int row = row0 + r;
        int b = row >> 11, s = row & 2047;
        Out[((size_t)(b*Hn + h)*2048 + s)*128 + d] = f2b(acc[i][j][r] * scale);
      }
    }
  }
}

// ---------------- flash attention (causal, GQA 2:1), 2-phase pipelined, PAIRED q-tiles ----------------

__device__ __forceinline__ int vt_idx(int d, int kv){
  return d*64 + ((((kv >> 3) + d + (d >> 3)) & 7) << 3) + (kv & 7);
}

__global__ __launch_bounds__(256) void flash_attn(
    const unsigned short* __restrict__ Q,   // (B,16,2048,128) roped, pre-scaled
    const unsigned short* __restrict__ Kb,  // (B,8,2048,128) roped, /RK
    const unsigned short* __restrict__ Vb,  // (B,8,2048,128) /RV
    unsigned short* __restrict__ O)         // (B*2048, 2048)
{
  __shared__ unsigned short Ks[64*128];     // swizzled content
  __shared__ unsigned short Vrow[64*128];   // linear row-major
  __shared__ unsigned short Vt[128*64];     // vt_idx layout
  __shared__ unsigned short Pl[4][16*64];

  const int tid = threadIdx.x;
  const int w = tid >> 6, lane = tid & 63;
  const int l16 = lane & 15, lg = lane >> 4;
  const int h = blockIdx.y, b = blockIdx.z;
  const int hkv = h >> 1;

  const size_t hbase  = ((size_t)(b*16 + h))*2048*128;
  const size_t kvbase = ((size_t)(b*8 + hkv))*2048*128;

  const int sR = w*16 + (lane >> 4);     // + i*4
  const int sC = (lane & 15) * 8;

  auto stage = [&](int kb){
    #pragma unroll
    for (int i = 0; i < 4; i++){
      int R = sR + i*4;
      const unsigned short* gk = Kb + kvbase + (size_t)(kb*64 + R)*128 + (sC ^ ((R & 7) << 3));
      gload_lds16(gk, &Ks[(w*16 + i*4)*128]);
      const unsigned short* gv = Vb + kvbase + (size_t)(kb*64 + R)*128 + sC;
      gload_lds16(gv, &Vrow[(w*16 + i*4)*128]);
    }
  };

  stage(0);
  __syncthreads();   // tile 0 resident

  const int tkv0 = (tid >> 4) * 4;   // transpose: thread handles 4 kv x 8 d
  const int td0  = (tid & 15) * 8;

  const int qtiles[2] = { (int)blockIdx.x, 31 - (int)blockIdx.x };

  for (int ph = 0; ph < 2; ph++){
    const int qe = qtiles[ph];
    const size_t qbase = hbase + (size_t)(qe*64 + w*16)*128;
    const int qrow0 = qe*64 + w*16 + lg*4;

    bf16x8 aq[4];
    #pragma unroll
    for (int t = 0; t < 4; t++)
      aq[t] = *reinterpret_cast<const bf16x8*>(&Q[qbase + (size_t)l16*128 + t*32 + lg*8]);

    f32x4 oac[8] = {};
    float mrow[4], lrow[4];
    #pragma unroll
    for (int r = 0; r < 4; r++){ mrow[r] = -1e30f; lrow[r] = 0.f; }

    for (int kb = 0; kb <= qe; kb++){
      bf16x8 vr0 = *reinterpret_cast<const bf16x8*>(&Vrow[(tkv0 + 0)*128 + td0]);
      bf16x8 vr1 = *reinterpret_cast<const bf16x8*>(&Vrow[(tkv0 + 1)*128 + td0]);
      bf16x8 vr2 = *reinterpret_cast<const bf16x8*>(&Vrow[(tkv0 + 2)*128 + td0]);
      bf16x8 vr3 = *reinterpret_cast<const bf16x8*>(&Vrow[(tkv0 + 3)*128 + td0]);

      f32x4 sac[4] = {};
      #pragma unroll
      for (int nt = 0; nt < 4; nt++){
        #pragma unroll
        for (int t = 0; t < 4; t++){
          int rowK = nt*16 + l16;
          int col  = t*32 + lg*8;
          bf16x8 bk = *reinterpret_cast<const bf16x8*>(&Ks[(rowK*128 + col) ^ ((rowK & 7) << 3)]);
          sac[nt] = MFMA_16x16x32(aq[t], bk, sac[nt]);
        }
      }

      #pragma unroll
      for (int j = 0; j < 8; j++){
        unsigned int lo = (unsigned int)(unsigned short)vr0[j] | ((unsigned int)(unsigned short)vr1[j] << 16);
        unsigned int hi = (unsigned int)(unsigned short)vr2[j] | ((unsigned int)(unsigned short)vr3[j] << 16);
        uint2 u; u.x = lo; u.y = hi;
        *reinterpret_cast<uint2*>(&Vt[vt_idx(td0 + j, tkv0)]) = u;
      }

      if (kb == qe){
        #pragma unroll
        for (int nt = 0; nt < 4; nt++){
          int kcol = kb*64 + nt*16 + l16;
          #pragma unroll
          for (int r = 0; r < 4; r++)
            if (kcol > qrow0 + r) sac[nt][r] = -1e30f;
        }
      }
      float corr[4];
      #pragma unroll
      for (int r = 0; r < 4; r++){
        float v = fmaxf(fmaxf(sac[0][r], sac[1][r]), fmaxf(sac[2][r], sac[3][r]));
        v = fmaxf(v, __shfl_xor(v, 1));
        v = fmaxf(v, __shfl_xor(v, 2));
        v = fmaxf(v, __shfl_xor(v, 4));
        v = fmaxf(v, __shfl_xor(v, 8));
        float mn = fmaxf(mrow[r], v);
        corr[r] = __expf(mrow[r] - mn);
        mrow[r] = mn;
      }
      float rs[4] = {0.f, 0.f, 0.f, 0.f};
      #pragma unroll
      for (int nt = 0; nt < 4; nt++){
        #pragma unroll
        for (int r = 0; r < 4; r++){
          float p = __expf(sac[nt][r] - mrow[r]);
          sac[nt][r] = p;
          rs[r] += p;
        }
      }
      #pragma unroll
      for (int r = 0; r < 4; r++){
        float v = rs[r];
        v += __shfl_xor(v, 1); v += __shfl_xor(v, 2); v += __shfl_xor(v, 4); v += __shfl_xor(v, 8);
        lrow[r] = lrow[r]*corr[r] + v;
      }
      #pragma unroll
      for (int dn = 0; dn < 8; dn++)
        #pragma unroll
        for (int r = 0; r < 4; r++) oac[dn][r] *= corr[r];

      #pragma unroll
      for (int nt = 0; nt < 4; nt++){
        #pragma unroll
        for (int r = 0; r < 4; r++){
          int row = lg*4 + r, col = nt*16 + l16;
          Pl[w][(row*64 + col) ^ ((row & 7) << 3)] = f2b(sac[nt][r]);
        }
      }

      __syncthreads();              // barrier B: Vt visible; no vmem in flight
      if (kb < qe) stage(kb + 1);
      else if (ph == 0) stage(0);

      #pragma unroll
      for (int t = 0; t < 2; t++){
        int colp = t*32 + lg*8;
        bf16x8 ap = *reinterpret_cast<const bf16x8*>(&Pl[w][(l16*64 + colp) ^ ((l16 & 7) << 3)]);
        #pragma unroll
        for (int dn = 0; dn < 8; dn++){
          int rowV = dn*16 + l16;
          bf16x8 bv = *reinterpret_cast<const bf16x8*>(&Vt[vt_idx(rowV, colp)]);
          oac[dn] = MFMA_16x16x32(ap, bv, oac[dn]);
        }
      }
      __syncthreads();              // barrier A: drains prefetch
    }

    #pragma unroll
    for (int dn = 0; dn < 8; dn++){
      #pragma unroll
      for (int r = 0; r < 4; r++){
        int row = qe*64 + w*16 + lg*4 + r;
        O[((size_t)(b*2048 + row))*2048 + h*128 + dn*16 + l16] = f2b(oac[dn][r] / lrow[r]);
      }
    }
  }
}

// ---------------- launcher ----------------

extern "C" void kernel_launch(void* const* d_in, const int* in_sizes, int n_in,
                              void* d_out, int out_size, void* d_ws, size_t ws_size,
                              hipStream_t stream)
{
  if (n_in < 10) return;
  const float* hidden = (const float*)d_in[0];
  const float* WAq = (const float*)d_in[1];
  const float* WAk = (const float*)d_in[2];
  const float* WAv = (const float*)d_in[3];
  const float* Bq  = (const float*)d_in[4];
  const float* Bk  = (const float*)d_in[5];
  const float* Bv  = (const float*)d_in[6];
  const float* Wo  = (const float*)d_in[7];
  const float* fcos = (const float*)d_in[8];
  const float* fsin = (const float*)d_in[9];
  float* out = (float*)d_out;

  char* p = (char*)d_ws;
  auto take = [&](size_t bytes){ char* q = p; p += (bytes + 255) & ~(size_t)255; return q; };
  unsigned short* Xb   = (unsigned short*)take((size_t)4096*2048*2);
  unsigned short* Wqkv = (unsigned short*)take((size_t)2048*2048*2);
  unsigned short* Wob  = (unsigned short*)take((size_t)2048*2048*2);
  unsigned short* Aqkv = (unsigned short*)take((size_t)4096*2048*2);
  unsigned short* Bqt  = (unsigned short*)take((size_t)16*128*64*2);
  unsigned short* Bkt  = (unsigned short*)take((size_t)8*128*64*2);
  unsigned short* Bvt  = (unsigned short*)take((size_t)8*128*64*2);
  unsigned short* qbuf = (unsigned short*)take((size_t)2*16*2048*128*2);
  unsigned short* kbuf = (unsigned short*)take((size_t)2*8*2048*128*2);
  unsigned short* vbuf = (unsigned short*)take((size_t)2*8*2048*128*2);
  unsigned short* aout = (unsigned short*)take((size_t)4096*2048*2);
  if ((size_t)(p - (char*)d_ws) > ws_size) return;

  auto cvt = [&](const float* s, unsigned short* d, size_t n){
    int n4 = (int)(n >> 2);
    int blocks = (n4 + 255) / 256; if (blocks > 4096) blocks = 4096;
    cvt_f32_bf16<<<blocks, 256, 0, stream>>>(s, d, n4);
  };
  cvt(hidden, Xb, (size_t)4096*2048);
  cvt(WAq, Wqkv,                       (size_t)1024*2048);
  cvt(WAk, Wqkv + (size_t)1024*2048,   (size_t)512*2048);
  cvt(WAv, Wqkv + (size_t)1536*2048,   (size_t)512*2048);
  cvt(Wo,  Wob, (size_t)2048*2048);
  cvt_factor_t<<<(16*64*128)/256, 256, 0, stream>>>(Bq, Bqt, 16*64*128);
  cvt_factor_t<<<(8*64*128)/256, 256, 0, stream>>>(Bk, Bkt, 8*64*128);
  cvt_factor_t<<<(8*64*128)/256, 256, 0, stream>>>(Bv, Bvt, 8*64*128);

  // A-factors: (4096,2048) = Xb @ Wqkv^T
  gemm_bt<0><<<dim3(32,16), 256, 0, stream>>>(Xb, Wqkv, (void*)Aqkv, 2048, 2048, 1.0f);

  const float SCALE = 0.08838834764831845f;  // 128^-0.5
  factor_gemm<<<dim3(32,16), 256, 0, stream>>>(Aqkv, Bqt, qbuf, 0,    16, SCALE/64.0f);
  factor_gemm<<<dim3(32,8),  256, 0, stream>>>(Aqkv, Bkt, kbuf, 1024, 8,  1.0f/64.0f);
  factor_gemm<<<dim3(32,8),  256, 0, stream>>>(Aqkv, Bvt, vbuf, 1536, 8,  1.0f/64.0f);

  rope_inplace<<<(32*2048*16)/256, 256, 0, stream>>>(qbuf, fcos, fsin, 32*2048*16);
  rope_inplace<<<(16*2048*16)/256, 256, 0, stream>>>(kbuf, fcos, fsin, 16*2048*16);

  flash_attn<<<dim3(16,16,2), 256, 0, stream>>>(qbuf, kbuf, vbuf, aout);

  // final: (4096,2048) fp32 = aout @ Wo^T
  gemm_bt<1><<<dim3(32,16), 256, 0, stream>>>(aout, Wob, (void*)out, 2048, 2048, 1.0f);
}

// Round 7
// 357.871 us; speedup vs baseline: 2.1104x; 1.0750x over previous
//
#include <hip/hip_runtime.h>
#include <hip/hip_bf16.h>

typedef __attribute__((ext_vector_type(8))) short bf16x8;
typedef __attribute__((ext_vector_type(4))) float f32x4;

#define MFMA_16x16x32(a,b,c) __builtin_amdgcn_mfma_f32_16x16x32_bf16((a),(b),(c),0,0,0)

__device__ __forceinline__ unsigned short f2b(float f){
  unsigned int u = __builtin_bit_cast(unsigned int, f);
  u = u + 0x7FFFu + ((u >> 16) & 1u);
  return (unsigned short)(u >> 16);
}
__device__ __forceinline__ float b2f(unsigned short h){
  unsigned int u = ((unsigned int)h) << 16;
  return __builtin_bit_cast(float, u);
}

__device__ __forceinline__ void gload_lds16(const unsigned short* g, unsigned short* l){
  __builtin_amdgcn_global_load_lds(
      (const __attribute__((address_space(1))) void*)g,
      (__attribute__((address_space(3))) void*)l, 16, 0, 0);
}

// ---------------- fused converters ----------------
// One kernel: hidden (2M f4), WAq (512K), WAk (256K), WAv (256K), Wo (1M) -> bf16.

__global__ void cvt_all(const float* __restrict__ hid, const float* __restrict__ wq,
                        const float* __restrict__ wk, const float* __restrict__ wv,
                        const float* __restrict__ wo,
                        unsigned short* __restrict__ Xb, unsigned short* __restrict__ Wqkv,
                        unsigned short* __restrict__ Wob){
  const int N0 = 2097152, N1 = 524288, N2 = 262144, N3 = 262144, N4 = 1048576;
  const int E1 = N0 + N1, E2 = E1 + N2, E3 = E2 + N3, E4 = E3 + N4;
  int i = blockIdx.x * blockDim.x + threadIdx.x;
  const int stride = gridDim.x * blockDim.x;
  for (; i < E4; i += stride){
    const float* s; unsigned short* d; int off;
    if (i < N0)      { s = hid; d = Xb;   off = i; }
    else if (i < E1) { s = wq;  d = Wqkv; off = i - N0; }
    else if (i < E2) { s = wk;  d = Wqkv; off = i - E1 + 524288;  s = wk;  }
    else if (i < E3) { s = wv;  d = Wqkv; off = i - E2 + 786432; }
    else             { s = wo;  d = Wob;  off = i - E3; }
    int src_off = (i < N0) ? i : (i < E1) ? (i - N0) : (i < E2) ? (i - E1) : (i < E3) ? (i - E2) : (i - E3);
    float4 v = reinterpret_cast<const float4*>(s)[src_off];
    ushort4 o;
    o.x = f2b(v.x); o.y = f2b(v.y); o.z = f2b(v.z); o.w = f2b(v.w);
    reinterpret_cast<ushort4*>(d)[off] = o;
  }
}

// all three factor transposes: (Hn,64,128) f32 -> (Hn,128,64) bf16; head ids 0-15 q, 16-23 k, 24-31 v
__global__ void cvt_factors(const float* __restrict__ Bq, const float* __restrict__ Bk,
                            const float* __restrict__ Bv,
                            unsigned short* __restrict__ Bqt, unsigned short* __restrict__ Bkt,
                            unsigned short* __restrict__ Bvt){
  int i = blockIdx.x * blockDim.x + threadIdx.x;   // 32*8192
  if (i >= 32*8192) return;
  int H = i >> 13, e = i & 8191;
  int d = e & 127, r = (e >> 7) & 63;
  const float* src; unsigned short* dst; int h;
  if (H < 16)      { src = Bq; dst = Bqt; h = H; }
  else if (H < 24) { src = Bk; dst = Bkt; h = H - 16; }
  else             { src = Bv; dst = Bvt; h = H - 24; }
  dst[(h << 13) + (d << 6) + r] = f2b(src[(size_t)(h << 13) + e]);
}

// ---------------- big GEMM-BT: C(MxN) = A(MxK) @ B(NxK)^T, bf16 in ----------------
// global_load_lds width-16 staging (T21 pre-swizzled source), double-buffered LDS,
// 2-phase: stage(next) issued BEFORE compute, ONE barrier per K-step.

template<int OUT_F32>
__global__ __launch_bounds__(256) void gemm_bt(
    const unsigned short* __restrict__ A, const unsigned short* __restrict__ B,
    void* __restrict__ Cv, int N, int K, float scale)
{
  __shared__ unsigned short As[2][128*64];
  __shared__ unsigned short Bs[2][128*64];
  const int tid = threadIdx.x;
  const int mb = blockIdx.x, nb = blockIdx.y;
  const int w = tid >> 6, lane = tid & 63;
  const int wr = w >> 1, wc = w & 1;
  const int l16 = lane & 15, lg = lane >> 4;

  f32x4 acc[4][4] = {};

  const unsigned short* Ap = A + (size_t)(mb*128)*K;
  const unsigned short* Bp = B + (size_t)(nb*128)*K;

  const int sRo = 32*w + (lane >> 3);           // + 8i
  const int sCo = ((lane & 7) ^ (lane >> 3)) << 3;
  const int ldsW = 2048*w;                      // + 512i

  auto stage = [&](int kt, int buf){
    const unsigned short* Ak = Ap + (size_t)kt*64 + sCo;
    const unsigned short* Bk = Bp + (size_t)kt*64 + sCo;
    #pragma unroll
    for (int i = 0; i < 4; i++)
      gload_lds16(Ak + (size_t)(sRo + 8*i)*K, &As[buf][ldsW + 512*i]);
    #pragma unroll
    for (int i = 0; i < 4; i++)
      gload_lds16(Bk + (size_t)(sRo + 8*i)*K, &Bs[buf][ldsW + 512*i]);
  };

  const int nkt = K >> 6;
  stage(0, 0);
  __syncthreads();

  int cur = 0;
  for (int kt = 0; kt < nkt; kt++){
    if (kt + 1 < nkt) stage(kt + 1, cur ^ 1);
    #pragma unroll
    for (int t = 0; t < 2; t++){
      bf16x8 af[4], bf[4];
      #pragma unroll
      for (int i = 0; i < 4; i++){
        int rowA = wr*64 + i*16 + l16;
        int col  = t*32 + lg*8;
        af[i] = *reinterpret_cast<const bf16x8*>(&As[cur][(rowA*64 + col) ^ ((rowA & 7) << 3)]);
        int rowB = wc*64 + i*16 + l16;
        bf[i] = *reinterpret_cast<const bf16x8*>(&Bs[cur][(rowB*64 + col) ^ ((rowB & 7) << 3)]);
      }
      #pragma unroll
      for (int i = 0; i < 4; i++)
        #pragma unroll
        for (int j = 0; j < 4; j++)
          acc[i][j] = MFMA_16x16x32(af[i], bf[j], acc[i][j]);
    }
    __syncthreads();
    cur ^= 1;
  }

  #pragma unroll
  for (int i = 0; i < 4; i++){
    #pragma unroll
    for (int j = 0; j < 4; j++){
      int row = mb*128 + wr*64 + i*16 + lg*4;
      int col = nb*128 + wc*64 + j*16 + l16;
      #pragma unroll
      for (int r = 0; r < 4; r++){
        float v = acc[i][j][r] * scale;
        if (OUT_F32) reinterpret_cast<float*>(Cv)[(size_t)(row + r)*N + col] = v;
        else reinterpret_cast<unsigned short*>(Cv)[(size_t)(row + r)*N + col] = f2b(v);
      }
    }
  }
}

// ---------------- fused factor GEMM + RoPE ----------------
// grid (32 mb, 32 H): H<16 q-heads, 16..23 k-heads, 24..31 v-heads.
// Wave w owns rows [w*32, w*32+32) x ALL 128 d (acc[2][8]) so the RoPE pair (d, d+64)
// is acc[i][j] / acc[i][j+4] in the SAME lane -> in-register f32 RoPE before bf16 store.

__global__ __launch_bounds__(256) void factor_rope(
    const unsigned short* __restrict__ A,    // (4096,2048) bf16
    const unsigned short* __restrict__ Bqt, const unsigned short* __restrict__ Bkt,
    const unsigned short* __restrict__ Bvt,
    unsigned short* __restrict__ qb, unsigned short* __restrict__ kb2,
    unsigned short* __restrict__ vb,
    const float* __restrict__ fc, const float* __restrict__ fs)
{
  __shared__ unsigned short As[128*64];
  __shared__ unsigned short Bs[128*64];
  const int tid = threadIdx.x, mb = blockIdx.x, H = blockIdx.y;
  const int w = tid >> 6, lane = tid & 63;
  const int l16 = lane & 15, lg = lane >> 4;
  const float SCALE = 0.08838834764831845f;  // 128^-0.5

  int h, coloff, Hn; const unsigned short* Bt; unsigned short* Out; float scale; bool rope;
  if (H < 16)      { h = H;      coloff = h*64;        Hn = 16; Bt = Bqt + (size_t)h*8192; Out = qb;  scale = SCALE/64.f; rope = true; }
  else if (H < 24) { h = H - 16; coloff = 1024 + h*64; Hn = 8;  Bt = Bkt + (size_t)h*8192; Out = kb2; scale = 1.f/64.f;   rope = true; }
  else             { h = H - 24; coloff = 1536 + h*64; Hn = 8;  Bt = Bvt + (size_t)h*8192; Out = vb;  scale = 1.f/64.f;   rope = false; }

  const int srow = tid >> 3;
  const int scol = (tid & 7) << 3;
  const unsigned short* Ap = A + (size_t)(mb*128)*2048 + coloff;

  #pragma unroll
  for (int c = 0; c < 4; c++){
    int r = srow + 32*c;
    int idx = (r*64 + scol) ^ ((r & 7) << 3);
    *reinterpret_cast<bf16x8*>(&As[idx]) = *reinterpret_cast<const bf16x8*>(Ap + (size_t)r*2048 + scol);
    *reinterpret_cast<bf16x8*>(&Bs[idx]) = *reinterpret_cast<const bf16x8*>(Bt + r*64 + scol);
  }
  __syncthreads();

  f32x4 acc[2][8] = {};
  #pragma unroll
  for (int t = 0; t < 2; t++){
    bf16x8 af[2], bf[8];
    #pragma unroll
    for (int i = 0; i < 2; i++){
      int rowA = w*32 + i*16 + l16;
      int col  = t*32 + lg*8;
      af[i] = *reinterpret_cast<const bf16x8*>(&As[(rowA*64 + col) ^ ((rowA & 7) << 3)]);
    }
    #pragma unroll
    for (int j = 0; j < 8; j++){
      int rowB = j*16 + l16;
      int col  = t*32 + lg*8;
      bf[j] = *reinterpret_cast<const bf16x8*>(&Bs[(rowB*64 + col) ^ ((rowB & 7) << 3)]);
    }
    #pragma unroll
    for (int i = 0; i < 2; i++)
      #pragma unroll
      for (int j = 0; j < 8; j++)
        acc[i][j] = MFMA_16x16x32(af[i], bf[j], acc[i][j]);
  }

  // epilogue: in-register RoPE on (d, d+64) pairs, then bf16 store
  #pragma unroll
  for (int i = 0; i < 2; i++){
    #pragma unroll
    for (int j = 0; j < 4; j++){
      int d = j*16 + l16;
      #pragma unroll
      for (int r = 0; r < 4; r++){
        int row = mb*128 + w*32 + i*16 + lg*4 + r;   // 0..4095
        int s = row & 2047, bb = row >> 11;
        float lo = acc[i][j][r] * scale;
        float hi = acc[i][j+4][r] * scale;
        float o1, o2;
        if (rope){
          float cc = fc[(size_t)s*64 + d];
          float ss = fs[(size_t)s*64 + d];
          o1 = lo*cc - hi*ss;
          o2 = lo*ss + hi*cc;
        } else { o1 = lo; o2 = hi; }
        size_t base = ((size_t)(bb*Hn + h)*2048 + s)*128;
        Out[base + d]      = f2b(o1);
        Out[base + 64 + d] = f2b(o2);
      }
    }
  }
}

// ---------------- flash attention (causal, GQA 2:1), 2-phase pipelined, PAIRED q-tiles ----------------

__device__ __forceinline__ int vt_idx(int d, int kv){
  return d*64 + ((((kv >> 3) + d + (d >> 3)) & 7) << 3) + (kv & 7);
}

__global__ __launch_bounds__(256) void flash_attn(
    const unsigned short* __restrict__ Q,   // (B,16,2048,128) roped, pre-scaled
    const unsigned short* __restrict__ Kb,  // (B,8,2048,128) roped, /RK
    const unsigned short* __restrict__ Vb,  // (B,8,2048,128) /RV
    unsigned short* __restrict__ O)         // (B*2048, 2048)
{
  __shared__ unsigned short Ks[64*128];
  __shared__ unsigned short Vrow[64*128];
  __shared__ unsigned short Vt[128*64];
  __shared__ unsigned short Pl[4][16*64];

  const int tid = threadIdx.x;
  const int w = tid >> 6, lane = tid & 63;
  const int l16 = lane & 15, lg = lane >> 4;
  const int h = blockIdx.y, b = blockIdx.z;
  const int hkv = h >> 1;

  const size_t hbase  = ((size_t)(b*16 + h))*2048*128;
  const size_t kvbase = ((size_t)(b*8 + hkv))*2048*128;

  const int sR = w*16 + (lane >> 4);     // + i*4
  const int sC = (lane & 15) * 8;

  auto stage = [&](int kb){
    #pragma unroll
    for (int i = 0; i < 4; i++){
      int R = sR + i*4;
      const unsigned short* gk = Kb + kvbase + (size_t)(kb*64 + R)*128 + (sC ^ ((R & 7) << 3));
      gload_lds16(gk, &Ks[(w*16 + i*4)*128]);
      const unsigned short* gv = Vb + kvbase + (size_t)(kb*64 + R)*128 + sC;
      gload_lds16(gv, &Vrow[(w*16 + i*4)*128]);
    }
  };

  stage(0);
  __syncthreads();

  const int tkv0 = (tid >> 4) * 4;
  const int td0  = (tid & 15) * 8;

  const int qtiles[2] = { (int)blockIdx.x, 31 - (int)blockIdx.x };

  for (int ph = 0; ph < 2; ph++){
    const int qe = qtiles[ph];
    const size_t qbase = hbase + (size_t)(qe*64 + w*16)*128;
    const int qrow0 = qe*64 + w*16 + lg*4;

    bf16x8 aq[4];
    #pragma unroll
    for (int t = 0; t < 4; t++)
      aq[t] = *reinterpret_cast<const bf16x8*>(&Q[qbase + (size_t)l16*128 + t*32 + lg*8]);

    f32x4 oac[8] = {};
    float mrow[4], lrow[4];
    #pragma unroll
    for (int r = 0; r < 4; r++){ mrow[r] = -1e30f; lrow[r] = 0.f; }

    for (int kb = 0; kb <= qe; kb++){
      bf16x8 vr0 = *reinterpret_cast<const bf16x8*>(&Vrow[(tkv0 + 0)*128 + td0]);
      bf16x8 vr1 = *reinterpret_cast<const bf16x8*>(&Vrow[(tkv0 + 1)*128 + td0]);
      bf16x8 vr2 = *reinterpret_cast<const bf16x8*>(&Vrow[(tkv0 + 2)*128 + td0]);
      bf16x8 vr3 = *reinterpret_cast<const bf16x8*>(&Vrow[(tkv0 + 3)*128 + td0]);

      f32x4 sac[4] = {};
      #pragma unroll
      for (int nt = 0; nt < 4; nt++){
        #pragma unroll
        for (int t = 0; t < 4; t++){
          int rowK = nt*16 + l16;
          int col  = t*32 + lg*8;
          bf16x8 bk = *reinterpret_cast<const bf16x8*>(&Ks[(rowK*128 + col) ^ ((rowK & 7) << 3)]);
          sac[nt] = MFMA_16x16x32(aq[t], bk, sac[nt]);
        }
      }

      #pragma unroll
      for (int j = 0; j < 8; j++){
        unsigned int lo = (unsigned int)(unsigned short)vr0[j] | ((unsigned int)(unsigned short)vr1[j] << 16);
        unsigned int hi = (unsigned int)(unsigned short)vr2[j] | ((unsigned int)(unsigned short)vr3[j] << 16);
        uint2 u; u.x = lo; u.y = hi;
        *reinterpret_cast<uint2*>(&Vt[vt_idx(td0 + j, tkv0)]) = u;
      }

      if (kb == qe){
        #pragma unroll
        for (int nt = 0; nt < 4; nt++){
          int kcol = kb*64 + nt*16 + l16;
          #pragma unroll
          for (int r = 0; r < 4; r++)
            if (kcol > qrow0 + r) sac[nt][r] = -1e30f;
        }
      }
      float corr[4];
      #pragma unroll
      for (int r = 0; r < 4; r++){
        float v = fmaxf(fmaxf(sac[0][r], sac[1][r]), fmaxf(sac[2][r], sac[3][r]));
        v = fmaxf(v, __shfl_xor(v, 1));
        v = fmaxf(v, __shfl_xor(v, 2));
        v = fmaxf(v, __shfl_xor(v, 4));
        v = fmaxf(v, __shfl_xor(v, 8));
        float mn = fmaxf(mrow[r], v);
        corr[r] = __expf(mrow[r] - mn);
        mrow[r] = mn;
      }
      float rs[4] = {0.f, 0.f, 0.f, 0.f};
      #pragma unroll
      for (int nt = 0; nt < 4; nt++){
        #pragma unroll
        for (int r = 0; r < 4; r++){
          float p = __expf(sac[nt][r] - mrow[r]);
          sac[nt][r] = p;
          rs[r] += p;
        }
      }
      #pragma unroll
      for (int r = 0; r < 4; r++){
        float v = rs[r];
        v += __shfl_xor(v, 1); v += __shfl_xor(v, 2); v += __shfl_xor(v, 4); v += __shfl_xor(v, 8);
        lrow[r] = lrow[r]*corr[r] + v;
      }
      #pragma unroll
      for (int dn = 0; dn < 8; dn++)
        #pragma unroll
        for (int r = 0; r < 4; r++) oac[dn][r] *= corr[r];

      #pragma unroll
      for (int nt = 0; nt < 4; nt++){
        #pragma unroll
        for (int r = 0; r < 4; r++){
          int row = lg*4 + r, col = nt*16 + l16;
          Pl[w][(row*64 + col) ^ ((row & 7) << 3)] = f2b(sac[nt][r]);
        }
      }

      __syncthreads();              // barrier B: Vt visible; no vmem in flight
      if (kb < qe) stage(kb + 1);
      else if (ph == 0) stage(0);

      #pragma unroll
      for (int t = 0; t < 2; t++){
        int colp = t*32 + lg*8;
        bf16x8 ap = *reinterpret_cast<const bf16x8*>(&Pl[w][(l16*64 + colp) ^ ((l16 & 7) << 3)]);
        #pragma unroll
        for (int dn = 0; dn < 8; dn++){
          int rowV = dn*16 + l16;
          bf16x8 bv = *reinterpret_cast<const bf16x8*>(&Vt[vt_idx(rowV, colp)]);
          oac[dn] = MFMA_16x16x32(ap, bv, oac[dn]);
        }
      }
      __syncthreads();              // barrier A: drains prefetch
    }

    #pragma unroll
    for (int dn = 0; dn < 8; dn++){
      #pragma unroll
      for (int r = 0; r < 4; r++){
        int row = qe*64 + w*16 + lg*4 + r;
        O[((size_t)(b*2048 + row))*2048 + h*128 + dn*16 + l16] = f2b(oac[dn][r] / lrow[r]);
      }
    }
  }
}

// ---------------- launcher ----------------

extern "C" void kernel_launch(void* const* d_in, const int* in_sizes, int n_in,
                              void* d_out, int out_size, void* d_ws, size_t ws_size,
                              hipStream_t stream)
{
  if (n_in < 10) return;
  const float* hidden = (const float*)d_in[0];
  const float* WAq = (const float*)d_in[1];
  const float* WAk = (const float*)d_in[2];
  const float* WAv = (const float*)d_in[3];
  const float* Bq  = (const float*)d_in[4];
  const float* Bk  = (const float*)d_in[5];
  const float* Bv  = (const float*)d_in[6];
  const float* Wo  = (const float*)d_in[7];
  const float* fcos = (const float*)d_in[8];
  const float* fsin = (const float*)d_in[9];
  float* out = (float*)d_out;

  char* p = (char*)d_ws;
  auto take = [&](size_t bytes){ char* q = p; p += (bytes + 255) & ~(size_t)255; return q; };
  unsigned short* Xb   = (unsigned short*)take((size_t)4096*2048*2);
  unsigned short* Wqkv = (unsigned short*)take((size_t)2048*2048*2);
  unsigned short* Wob  = (unsigned short*)take((size_t)2048*2048*2);
  unsigned short* Aqkv = (unsigned short*)take((size_t)4096*2048*2);
  unsigned short* Bqt  = (unsigned short*)take((size_t)16*128*64*2);
  unsigned short* Bkt  = (unsigned short*)take((size_t)8*128*64*2);
  unsigned short* Bvt  = (unsigned short*)take((size_t)8*128*64*2);
  unsigned short* qbuf = (unsigned short*)take((size_t)2*16*2048*128*2);
  unsigned short* kbuf = (unsigned short*)take((size_t)2*8*2048*128*2);
  unsigned short* vbuf = (unsigned short*)take((size_t)2*8*2048*128*2);
  unsigned short* aout = (unsigned short*)take((size_t)4096*2048*2);
  if ((size_t)(p - (char*)d_ws) > ws_size) return;

  cvt_all<<<4096, 256, 0, stream>>>(hidden, WAq, WAk, WAv, Wo, Xb, Wqkv, Wob);
  cvt_factors<<<1024, 256, 0, stream>>>(Bq, Bk, Bv, Bqt, Bkt, Bvt);

  // A-factors: (4096,2048) = Xb @ Wqkv^T
  gemm_bt<0><<<dim3(32,16), 256, 0, stream>>>(Xb, Wqkv, (void*)Aqkv, 2048, 2048, 1.0f);

  // fused per-head factor GEMMs + RoPE
  factor_rope<<<dim3(32,32), 256, 0, stream>>>(Aqkv, Bqt, Bkt, Bvt, qbuf, kbuf, vbuf, fcos, fsin);

  flash_attn<<<dim3(16,16,2), 256, 0, stream>>>(qbuf, kbuf, vbuf, aout);

  // final: (4096,2048) fp32 = aout @ Wo^T
  gemm_bt<1><<<dim3(32,16), 256, 0, stream>>>(aout, Wob, (void*)out, 2048, 2048, 1.0f);
}